// Round 8
// baseline (405.697 us; speedup 1.0000x reference)
//
#include <hip/hip_runtime.h>
#include <hip/hip_bf16.h>

// ---------------------------------------------------------------------------
// ResidualBlock: GMMConv(x)->BN->ELU->GMMConv->BN  +  GMMConv_sc(x)->BN ; ELU
// N=50000, E=800000, C=64, K_main=5, K_sc=1.
// Round 8: agg is gather-traffic + chain-latency bound. (1) bf16 feature
// gathers (x converted once; norm_elu emits h_bf) halve gather bytes;
// (2) 16B edge records {6x bf16 w, src} = ONE uint4 load/edge; (3) agg loop
// software-pipelined (next block's records load under current FMAs).
// ---------------------------------------------------------------------------

#define EPS_SIGMA 1e-15f
#define BN_EPS    1e-5f

typedef unsigned short ushortT;
typedef unsigned int uintT;

__device__ __forceinline__ ushortT f2bf(float f) {
  uintT b = __float_as_uint(f);
  b += 0x7FFFu + ((b >> 16) & 1u);   // round-to-nearest-even
  return (ushortT)(b >> 16);
}
__device__ __forceinline__ float bf2f(ushortT u) {
  return __uint_as_float(((uintT)u) << 16);
}
__device__ __forceinline__ uintT pk2(float a, float b) {
  return (uintT)f2bf(a) | ((uintT)f2bf(b) << 16);
}

// --- dtype detect: int64 edge_index has all-zero high words -----------------
__global__ void detect_kernel(const void* ei, int* flag) {
  const int* p = (const int*)ei;
  __shared__ int bad;
  if (threadIdx.x == 0) bad = 0;
  __syncthreads();
  if (p[threadIdx.x * 2 + 1] != 0) atomicAdd(&bad, 1);
  __syncthreads();
  if (threadIdx.x == 0) *flag = (bad == 0);  // 1 => int64 layout
}

__device__ __forceinline__ int load_idx(const void* ei, size_t pos, int is64) {
  if (is64) return (int)((const long long*)ei)[pos];
  return ((const int*)ei)[pos];
}

// --- fp32 -> bf16 convert (vectorized) --------------------------------------
__global__ void to_bf16(const float* __restrict__ in, ushortT* __restrict__ out, int total) {
  int idx = (blockIdx.x * 256 + threadIdx.x) * 4;
  if (idx + 3 < total) {
    float4 v = *(const float4*)&in[idx];
    ushortT o[4] = {f2bf(v.x), f2bf(v.y), f2bf(v.z), f2bf(v.w)};
    *(uint2*)&out[idx] = *(const uint2*)o;
  } else {
    for (int j = 0; j < 4 && idx + j < total; ++j) out[idx + j] = f2bf(in[idx + j]);
  }
}

// --- CSR build: hist also records each edge's within-bucket position --------
__global__ void hist_kernel(const void* ei, int E, const int* flag, int* cnt,
                            int* __restrict__ pos) {
  int e = blockIdx.x * blockDim.x + threadIdx.x;
  if (e >= E) return;
  int d = load_idx(ei, (size_t)E + e, *flag);
  pos[e] = atomicAdd(&cnt[d], 1);
}

__global__ __launch_bounds__(256) void scan1(const int* __restrict__ cnt,
                                             int* __restrict__ row_ptr,
                                             int* __restrict__ partials, int n) {
  int tid = threadIdx.x;
  int base = blockIdx.x * 2048 + tid * 8;
  int v[8], pre[8];
  int run = 0;
#pragma unroll
  for (int j = 0; j < 8; ++j) {
    int idx = base + j;
    v[j] = (idx < n) ? cnt[idx] : 0;
    pre[j] = run;
    run += v[j];
  }
  __shared__ int sd[256];
  sd[tid] = run;
  __syncthreads();
  for (int off = 1; off < 256; off <<= 1) {
    int t = (tid >= off) ? sd[tid - off] : 0;
    __syncthreads();
    sd[tid] += t;
    __syncthreads();
  }
  int excl = sd[tid] - run;
#pragma unroll
  for (int j = 0; j < 8; ++j) {
    int idx = base + j;
    if (idx < n) row_ptr[idx] = excl + pre[j];
  }
  if (tid == 255) partials[blockIdx.x] = sd[255];
}

__global__ void scan2(int* partials, int nb, int* row_ptr, int n) {
  __shared__ int sd[256];
  int tid = threadIdx.x;
  int v = (tid < nb) ? partials[tid] : 0;
  sd[tid] = v;
  __syncthreads();
  for (int off = 1; off < 256; off <<= 1) {
    int t = (tid >= off) ? sd[tid - off] : 0;
    __syncthreads();
    sd[tid] += t;
    __syncthreads();
  }
  if (tid < nb) partials[tid] = sd[tid] - v;
  if (tid == nb - 1) row_ptr[n] = sd[tid];
}

__global__ void scan3(int* __restrict__ row_ptr, const int* __restrict__ partials, int n) {
  int i = blockIdx.x * 256 + threadIdx.x;
  if (i < n) row_ptr[i] += partials[i >> 11];
}

// --- scatter + gaussian weights: ONE 16B record per edge per layer ----------
// rec = {pk(w0,w1), pk(w2,w3), pk(w4,w5), src}
__global__ __launch_bounds__(256) void scatter_wgt(
    const void* ei, const float* __restrict__ ea, int E, const int* flag,
    const int* __restrict__ row_ptr, const int* __restrict__ pos,
    const float* __restrict__ mu1, const float* __restrict__ sig1,
    const float* __restrict__ mus, const float* __restrict__ sigs,
    const float* __restrict__ mu2, const float* __restrict__ sig2,
    uint4* __restrict__ wbuf1, uint4* __restrict__ wbuf2) {
  int e = blockIdx.x * 256 + threadIdx.x;
  if (e >= E) return;
  int is64 = *flag;
  int s = load_idx(ei, (size_t)e, is64);
  int d = load_idx(ei, (size_t)E + e, is64);
  int slot = row_ptr[d] + pos[e];
  float p = ea[e];
  float w1[6], w2[5];
#pragma unroll
  for (int k = 0; k < 5; ++k) {
    float sg = sig1[k], df = p - mu1[k];
    w1[k] = __expf(-0.5f / (EPS_SIGMA + sg * sg) * df * df);
  }
  {
    float sg = sigs[0], df = p - mus[0];
    w1[5] = __expf(-0.5f / (EPS_SIGMA + sg * sg) * df * df);
  }
#pragma unroll
  for (int k = 0; k < 5; ++k) {
    float sg = sig2[k], df = p - mu2[k];
    w2[k] = __expf(-0.5f / (EPS_SIGMA + sg * sg) * df * df);
  }
  wbuf1[slot] = make_uint4(pk2(w1[0], w1[1]), pk2(w1[2], w1[3]), pk2(w1[4], w1[5]), (uintT)s);
  wbuf2[slot] = make_uint4(pk2(w2[0], w2[1]), pk2(w2[2], w2[3]), pk2(w2[4], 0.f), (uintT)s);
}

// --- aggregation: wave per node, lane = channel, pipelined 8-edge blocks ----
template <int KT>
__device__ __forceinline__ void rec_fma(float* acc, uint4 r, float xv) {
  acc[0] = fmaf(bf2f((ushortT)(r.x & 0xffffu)), xv, acc[0]);
  if (KT > 1) acc[1] = fmaf(bf2f((ushortT)(r.x >> 16)), xv, acc[1]);
  if (KT > 2) acc[2] = fmaf(bf2f((ushortT)(r.y & 0xffffu)), xv, acc[2]);
  if (KT > 3) acc[3] = fmaf(bf2f((ushortT)(r.y >> 16)), xv, acc[3]);
  if (KT > 4) acc[4] = fmaf(bf2f((ushortT)(r.z & 0xffffu)), xv, acc[4]);
  if (KT > 5) acc[5] = fmaf(bf2f((ushortT)(r.z >> 16)), xv, acc[5]);
}

template <int KT>
__global__ __launch_bounds__(256) void agg_pre(const ushortT* __restrict__ feat,
                                               const int* __restrict__ row_ptr,
                                               const uint4* __restrict__ wbuf,
                                               ushortT* __restrict__ out, int n, int ldo) {
  int node = blockIdx.x * 4 + (threadIdx.x >> 6);
  int lane = threadIdx.x & 63;
  if (node >= n) return;
  int beg = row_ptr[node], end = row_ptr[node + 1];
  float acc[KT];
#pragma unroll
  for (int k = 0; k < KT; ++k) acc[k] = 0.f;
  int i = beg;
  if (i + 8 <= end) {
    uint4 rec[8];
#pragma unroll
    for (int j = 0; j < 8; ++j) rec[j] = wbuf[i + j];
    i += 8;
    while (true) {
      float xv[8];
#pragma unroll
      for (int j = 0; j < 8; ++j)
        xv[j] = bf2f(feat[((size_t)rec[j].w << 6) + lane]);
      bool more = (i + 8 <= end);
      uint4 nxt[8];
      if (more) {
#pragma unroll
        for (int j = 0; j < 8; ++j) nxt[j] = wbuf[i + j];
      }
#pragma unroll
      for (int j = 0; j < 8; ++j) rec_fma<KT>(acc, rec[j], xv[j]);
      if (!more) break;
#pragma unroll
      for (int j = 0; j < 8; ++j) rec[j] = nxt[j];
      i += 8;
    }
  }
  for (; i < end; ++i) {
    uint4 r = wbuf[i];
    float xv = bf2f(feat[((size_t)r.w << 6) + lane]);
    rec_fma<KT>(acc, r, xv);
  }
  int degi = end - beg;
  float invdeg = 1.0f / (float)(degi > 1 ? degi : 1);
  size_t o = (size_t)node * ldo + lane;
#pragma unroll
  for (int k = 0; k < KT; ++k) out[o + k * 64] = f2bf(acc[k] * invdeg);
}

// --- weight prep: Bout[(K*64+64) x 64] = [rearranged G ; root] ---------------
__global__ void prep_cat(const float* __restrict__ g, const float* __restrict__ root,
                         float* __restrict__ Bout, int K) {
  int idx = blockIdx.x * 256 + threadIdx.x;
  int total = (K + 1) * 64 * 64;
  if (idx >= total) return;
  int r = idx >> 6, c = idx & 63;
  float v;
  if (r < K * 64) {
    int k = r >> 6, i = r & 63;
    v = g[i * (K * 64) + k * 64 + c];
  } else {
    v = root[(r - K * 64) * 64 + c];
  }
  Bout[idx] = v;
}

// --- GEMM: C[M,64] = [A1(K1 bf16)|A2(64 fp32)]@B + bias ; fused BN stats ----
__global__ __launch_bounds__(256) void gemm_fused(const ushortT* __restrict__ A1, int lda1,
                                                  int K1, const float* __restrict__ A2,
                                                  const float* __restrict__ B,
                                                  const float* __restrict__ bias,
                                                  float* __restrict__ C, int M,
                                                  float* sums, float* sumsq) {
  __shared__ float As[64][68];
  __shared__ float Bs[64][64];
  __shared__ float red[16][64];
  int tile_m = blockIdx.x * 64;
  int tid = threadIdx.x, tx = tid & 15, ty = tid >> 4;
  float acc[4][4] = {};
  int nch = K1 >> 6;
  for (int ch = 0; ch <= nch; ++ch) {
    if (ch < nch) {
      int kb = ch * 64;
#pragma unroll
      for (int i = 0; i < 2; ++i) {
        int slot = tid + i * 256;          // 0..511
        int r = slot >> 3, c8 = (slot & 7) * 8;
        uint4 v = make_uint4(0u, 0u, 0u, 0u);
        if (tile_m + r < M)
          v = *(const uint4*)&A1[(size_t)(tile_m + r) * lda1 + kb + c8];
        const ushortT* us = (const ushortT*)&v;
        float f[8];
#pragma unroll
        for (int j = 0; j < 8; ++j) f[j] = bf2f(us[j]);
        *(float4*)&As[r][c8]     = make_float4(f[0], f[1], f[2], f[3]);
        *(float4*)&As[r][c8 + 4] = make_float4(f[4], f[5], f[6], f[7]);
      }
    } else {
#pragma unroll
      for (int i = 0; i < 4; ++i) {
        int idx = tid + i * 256, r = idx >> 4, c4 = idx & 15;
        float4 v = make_float4(0.f, 0.f, 0.f, 0.f);
        if (tile_m + r < M) v = *(const float4*)&A2[(size_t)(tile_m + r) * 64 + c4 * 4];
        *(float4*)&As[r][c4 * 4] = v;
      }
    }
#pragma unroll
    for (int i = 0; i < 4; ++i) {
      int idx = tid + i * 256, r = idx >> 4, c4 = idx & 15;
      *(float4*)&Bs[r][c4 * 4] = *(const float4*)&B[(size_t)(ch * 64 + r) * 64 + c4 * 4];
    }
    __syncthreads();
#pragma unroll
    for (int k = 0; k < 64; k += 4) {
      float4 b0 = *(const float4*)&Bs[k + 0][tx * 4];
      float4 b1v = *(const float4*)&Bs[k + 1][tx * 4];
      float4 b2 = *(const float4*)&Bs[k + 2][tx * 4];
      float4 b3 = *(const float4*)&Bs[k + 3][tx * 4];
#pragma unroll
      for (int i = 0; i < 4; ++i) {
        float4 a = *(const float4*)&As[ty * 4 + i][k];
        acc[i][0] = fmaf(a.x, b0.x, acc[i][0]);
        acc[i][1] = fmaf(a.x, b0.y, acc[i][1]);
        acc[i][2] = fmaf(a.x, b0.z, acc[i][2]);
        acc[i][3] = fmaf(a.x, b0.w, acc[i][3]);
        acc[i][0] = fmaf(a.y, b1v.x, acc[i][0]);
        acc[i][1] = fmaf(a.y, b1v.y, acc[i][1]);
        acc[i][2] = fmaf(a.y, b1v.z, acc[i][2]);
        acc[i][3] = fmaf(a.y, b1v.w, acc[i][3]);
        acc[i][0] = fmaf(a.z, b2.x, acc[i][0]);
        acc[i][1] = fmaf(a.z, b2.y, acc[i][1]);
        acc[i][2] = fmaf(a.z, b2.z, acc[i][2]);
        acc[i][3] = fmaf(a.z, b2.w, acc[i][3]);
        acc[i][0] = fmaf(a.w, b3.x, acc[i][0]);
        acc[i][1] = fmaf(a.w, b3.y, acc[i][1]);
        acc[i][2] = fmaf(a.w, b3.z, acc[i][2]);
        acc[i][3] = fmaf(a.w, b3.w, acc[i][3]);
      }
    }
    __syncthreads();
  }
  float cs[4] = {}, cq[4] = {};
#pragma unroll
  for (int i = 0; i < 4; ++i) {
    int r = tile_m + ty * 4 + i;
    if (r < M) {
      int cc = tx * 4;
      float ov[4];
#pragma unroll
      for (int j = 0; j < 4; ++j) {
        ov[j] = acc[i][j] + bias[cc + j];
        cs[j] += ov[j];
        cq[j] = fmaf(ov[j], ov[j], cq[j]);
      }
      *(float4*)&C[(size_t)r * 64 + cc] = make_float4(ov[0], ov[1], ov[2], ov[3]);
    }
  }
#pragma unroll
  for (int j = 0; j < 4; ++j) red[ty][tx * 4 + j] = cs[j];
  __syncthreads();
  if (tid < 64) {
    float t = 0.f;
#pragma unroll
    for (int g = 0; g < 16; ++g) t += red[g][tid];
    atomicAdd(&sums[tid], t);
  }
  __syncthreads();
#pragma unroll
  for (int j = 0; j < 4; ++j) red[ty][tx * 4 + j] = cq[j];
  __syncthreads();
  if (tid < 64) {
    float t = 0.f;
#pragma unroll
    for (int g = 0; g < 16; ++g) t += red[g][tid];
    atomicAdd(&sumsq[tid], t);
  }
}

// --- batchnorm scale/shift + epilogues --------------------------------------
__global__ void bn_final(const float* sum, const float* sumsq, const float* gamma,
                         const float* beta, int n, float* scale, float* shift) {
  int c = threadIdx.x;
  float m = sum[c] / (float)n;
  float v = sumsq[c] / (float)n - m * m;
  float r = rsqrtf(v + BN_EPS);
  float s = r * gamma[c];
  scale[c] = s;
  shift[c] = beta[c] - m * s;
}

// normalize + ELU; writes fp32 (GEMM A2 operand) and bf16 (agg gather feed)
__global__ void norm_elu(float* h, ushortT* __restrict__ h_bf,
                         const float* __restrict__ scale,
                         const float* __restrict__ shift, int total) {
  int i = blockIdx.x * 256 + threadIdx.x;
  if (i >= total) return;
  int c = i & 63;
  float v = h[i] * scale[c] + shift[c];
  v = v > 0.f ? v : expm1f(v);
  h[i] = v;
  h_bf[i] = f2bf(v);
}

__global__ void final_kernel(const float* __restrict__ h2, const float* __restrict__ sc,
                             const float* __restrict__ s2, const float* __restrict__ t2,
                             const float* __restrict__ ss, const float* __restrict__ ts,
                             float* __restrict__ out, int total) {
  int i = blockIdx.x * 256 + threadIdx.x;
  if (i >= total) return;
  int c = i & 63;
  float v = h2[i] * s2[c] + t2[c] + sc[i] * ss[c] + ts[c];
  out[i] = v > 0.f ? v : expm1f(v);
}

// ---------------------------------------------------------------------------
extern "C" void kernel_launch(void* const* d_in, const int* in_sizes, int n_in,
                              void* d_out, int out_size, void* d_ws, size_t ws_size,
                              hipStream_t stream) {
  const float* x    = (const float*)d_in[0];
  const void*  ei   = d_in[1];
  const float* ea   = (const float*)d_in[2];
  const float* g1   = (const float*)d_in[3];
  const float* mu1  = (const float*)d_in[4];
  const float* sig1 = (const float*)d_in[5];
  const float* root1= (const float*)d_in[6];
  const float* b1   = (const float*)d_in[7];
  const float* gam1 = (const float*)d_in[8];
  const float* bet1 = (const float*)d_in[9];
  const float* g2   = (const float*)d_in[10];
  const float* mu2  = (const float*)d_in[11];
  const float* sig2 = (const float*)d_in[12];
  const float* root2= (const float*)d_in[13];
  const float* b2   = (const float*)d_in[14];
  const float* gam2 = (const float*)d_in[15];
  const float* bet2 = (const float*)d_in[16];
  const float* gs   = (const float*)d_in[17];
  const float* mus  = (const float*)d_in[18];
  const float* sigs = (const float*)d_in[19];
  const float* roots= (const float*)d_in[20];
  const float* bs   = (const float*)d_in[21];
  const float* gams = (const float*)d_in[22];
  const float* bets = (const float*)d_in[23];

  int N = in_sizes[0] / 64;
  int E = in_sizes[1] / 2;

  char* w = (char*)d_ws;
  auto alloc = [&](size_t bytes) {
    char* p = w;
    w += (bytes + 255) & ~(size_t)255;
    return p;
  };
  int*     flag    = (int*)alloc(256);
  int*     cnt     = (int*)alloc((size_t)N * 4);
  int*     row_ptr = (int*)alloc((size_t)(N + 1) * 4);
  int*     partials= (int*)alloc(256 * 4);
  int*     pos     = (int*)alloc((size_t)E * 4);
  uint4*   wbuf1   = (uint4*)alloc((size_t)E * 16);       // layer1+sc records
  uint4*   wbuf2   = (uint4*)alloc((size_t)E * 16);       // layer2 records
  ushortT* Abuf    = (ushortT*)alloc((size_t)N * 384 * 2); // agg outputs (bf16)
  ushortT* x_bf    = (ushortT*)alloc((size_t)N * 64 * 2);
  ushortT* h_bf    = (ushortT*)alloc((size_t)N * 64 * 2);
  float*   h       = (float*)alloc((size_t)N * 64 * 4);
  float*   h2      = (float*)alloc((size_t)N * 64 * 4);
  float*   scb     = (float*)alloc((size_t)N * 64 * 4);
  float*   B1cat   = (float*)alloc(384 * 64 * 4);
  float*   B2cat   = (float*)alloc(384 * 64 * 4);
  float*   Bsc     = (float*)alloc(128 * 64 * 4);
  float*   stats   = (float*)alloc(12 * 64 * 4);

  hipMemsetAsync(cnt, 0, (size_t)N * 4, stream);
  hipMemsetAsync(stats, 0, 12 * 64 * 4, stream);

  int eb = (E + 255) / 256;
  int nb1 = (N + 2047) / 2048;
  int nb_elem = (N * 64 + 255) / 256;

  prep_cat<<<(6 * 4096 + 255) / 256, 256, 0, stream>>>(g1, root1, B1cat, 5);
  prep_cat<<<(6 * 4096 + 255) / 256, 256, 0, stream>>>(g2, root2, B2cat, 5);
  prep_cat<<<(2 * 4096 + 255) / 256, 256, 0, stream>>>(gs, roots, Bsc, 1);
  to_bf16<<<(N * 64 / 4 + 255) / 256, 256, 0, stream>>>(x, x_bf, N * 64);

  detect_kernel<<<1, 256, 0, stream>>>(ei, flag);
  hist_kernel<<<eb, 256, 0, stream>>>(ei, E, flag, cnt, pos);
  scan1<<<nb1, 256, 0, stream>>>(cnt, row_ptr, partials, N);
  scan2<<<1, 256, 0, stream>>>(partials, nb1, row_ptr, N);
  scan3<<<(N + 255) / 256, 256, 0, stream>>>(row_ptr, partials, N);
  scatter_wgt<<<eb, 256, 0, stream>>>(ei, ea, E, flag, row_ptr, pos,
                                      mu1, sig1, mus, sigs, mu2, sig2, wbuf1, wbuf2);

  int mtiles = (N + 63) / 64;
  int nb_node = (N + 3) / 4;

  // ---- layer1 + shortcut ----
  agg_pre<6><<<nb_node, 256, 0, stream>>>(x_bf, row_ptr, wbuf1, Abuf, N, 384);
  gemm_fused<<<mtiles, 256, 0, stream>>>(Abuf, 384, 320, x, B1cat, b1, h, N,
                                         stats + 0 * 64, stats + 1 * 64);
  gemm_fused<<<mtiles, 256, 0, stream>>>(Abuf + 320, 384, 64, x, Bsc, bs, scb, N,
                                         stats + 4 * 64, stats + 5 * 64);
  bn_final<<<1, 64, 0, stream>>>(stats + 0 * 64, stats + 1 * 64, gam1, bet1, N,
                                 stats + 6 * 64, stats + 7 * 64);
  norm_elu<<<nb_elem, 256, 0, stream>>>(h, h_bf, stats + 6 * 64, stats + 7 * 64, N * 64);

  // ---- layer2 ----
  agg_pre<5><<<nb_node, 256, 0, stream>>>(h_bf, row_ptr, wbuf2, Abuf, N, 320);
  gemm_fused<<<mtiles, 256, 0, stream>>>(Abuf, 320, 320, h, B2cat, b2, h2, N,
                                         stats + 2 * 64, stats + 3 * 64);

  bn_final<<<1, 64, 0, stream>>>(stats + 2 * 64, stats + 3 * 64, gam2, bet2, N,
                                 stats + 8 * 64, stats + 9 * 64);
  bn_final<<<1, 64, 0, stream>>>(stats + 4 * 64, stats + 5 * 64, gams, bets, N,
                                 stats + 10 * 64, stats + 11 * 64);

  final_kernel<<<nb_elem, 256, 0, stream>>>(h2, scb, stats + 8 * 64, stats + 9 * 64,
                                            stats + 10 * 64, stats + 11 * 64,
                                            (float*)d_out, N * 64);
}

// Round 9
// 328.543 us; speedup vs baseline: 1.2348x; 1.2348x over previous
//
#include <hip/hip_runtime.h>
#include <hip/hip_bf16.h>

// ---------------------------------------------------------------------------
// ResidualBlock: GMMConv(x)->BN->ELU->GMMConv->BN  +  GMMConv_sc(x)->BN ; ELU
// N=50000, E=800000, C=64, K_main=5, K_sc=1.
// Round 9: agg perf tracks OCCUPANCY (R5/R7/R8: 70/44/25% -> 68/74/86us).
// Dropped the explicit pipeline (VGPR down); wave now processes 2 edges per
// gather instruction (half-wave per edge, uint = 2 bf16 channels per lane),
// acc in float2[KT], shfl_xor(32) merge. Unroll 4 pairs = 8 edges in flight.
// ---------------------------------------------------------------------------

#define EPS_SIGMA 1e-15f
#define BN_EPS    1e-5f

typedef unsigned short ushortT;
typedef unsigned int uintT;

__device__ __forceinline__ ushortT f2bf(float f) {
  uintT b = __float_as_uint(f);
  b += 0x7FFFu + ((b >> 16) & 1u);   // round-to-nearest-even
  return (ushortT)(b >> 16);
}
__device__ __forceinline__ float bf2f(ushortT u) {
  return __uint_as_float(((uintT)u) << 16);
}
__device__ __forceinline__ uintT pk2(float a, float b) {
  return (uintT)f2bf(a) | ((uintT)f2bf(b) << 16);
}

// --- dtype detect: int64 edge_index has all-zero high words -----------------
__global__ void detect_kernel(const void* ei, int* flag) {
  const int* p = (const int*)ei;
  __shared__ int bad;
  if (threadIdx.x == 0) bad = 0;
  __syncthreads();
  if (p[threadIdx.x * 2 + 1] != 0) atomicAdd(&bad, 1);
  __syncthreads();
  if (threadIdx.x == 0) *flag = (bad == 0);  // 1 => int64 layout
}

__device__ __forceinline__ int load_idx(const void* ei, size_t pos, int is64) {
  if (is64) return (int)((const long long*)ei)[pos];
  return ((const int*)ei)[pos];
}

// --- fp32 -> bf16 convert (vectorized) --------------------------------------
__global__ void to_bf16(const float* __restrict__ in, ushortT* __restrict__ out, int total) {
  int idx = (blockIdx.x * 256 + threadIdx.x) * 4;
  if (idx + 3 < total) {
    float4 v = *(const float4*)&in[idx];
    ushortT o[4] = {f2bf(v.x), f2bf(v.y), f2bf(v.z), f2bf(v.w)};
    *(uint2*)&out[idx] = *(const uint2*)o;
  } else {
    for (int j = 0; j < 4 && idx + j < total; ++j) out[idx + j] = f2bf(in[idx + j]);
  }
}

// --- CSR build: hist also records each edge's within-bucket position --------
__global__ void hist_kernel(const void* ei, int E, const int* flag, int* cnt,
                            int* __restrict__ pos) {
  int e = blockIdx.x * blockDim.x + threadIdx.x;
  if (e >= E) return;
  int d = load_idx(ei, (size_t)E + e, *flag);
  pos[e] = atomicAdd(&cnt[d], 1);
}

__global__ __launch_bounds__(256) void scan1(const int* __restrict__ cnt,
                                             int* __restrict__ row_ptr,
                                             int* __restrict__ partials, int n) {
  int tid = threadIdx.x;
  int base = blockIdx.x * 2048 + tid * 8;
  int v[8], pre[8];
  int run = 0;
#pragma unroll
  for (int j = 0; j < 8; ++j) {
    int idx = base + j;
    v[j] = (idx < n) ? cnt[idx] : 0;
    pre[j] = run;
    run += v[j];
  }
  __shared__ int sd[256];
  sd[tid] = run;
  __syncthreads();
  for (int off = 1; off < 256; off <<= 1) {
    int t = (tid >= off) ? sd[tid - off] : 0;
    __syncthreads();
    sd[tid] += t;
    __syncthreads();
  }
  int excl = sd[tid] - run;
#pragma unroll
  for (int j = 0; j < 8; ++j) {
    int idx = base + j;
    if (idx < n) row_ptr[idx] = excl + pre[j];
  }
  if (tid == 255) partials[blockIdx.x] = sd[255];
}

__global__ void scan2(int* partials, int nb, int* row_ptr, int n) {
  __shared__ int sd[256];
  int tid = threadIdx.x;
  int v = (tid < nb) ? partials[tid] : 0;
  sd[tid] = v;
  __syncthreads();
  for (int off = 1; off < 256; off <<= 1) {
    int t = (tid >= off) ? sd[tid - off] : 0;
    __syncthreads();
    sd[tid] += t;
    __syncthreads();
  }
  if (tid < nb) partials[tid] = sd[tid] - v;
  if (tid == nb - 1) row_ptr[n] = sd[tid];
}

__global__ void scan3(int* __restrict__ row_ptr, const int* __restrict__ partials, int n) {
  int i = blockIdx.x * 256 + threadIdx.x;
  if (i < n) row_ptr[i] += partials[i >> 11];
}

// --- scatter + gaussian weights: ONE 16B record per edge per layer ----------
// rec = {pk(w0,w1), pk(w2,w3), pk(w4,w5), src}
__global__ __launch_bounds__(256) void scatter_wgt(
    const void* ei, const float* __restrict__ ea, int E, const int* flag,
    const int* __restrict__ row_ptr, const int* __restrict__ pos,
    const float* __restrict__ mu1, const float* __restrict__ sig1,
    const float* __restrict__ mus, const float* __restrict__ sigs,
    const float* __restrict__ mu2, const float* __restrict__ sig2,
    uint4* __restrict__ wbuf1, uint4* __restrict__ wbuf2) {
  int e = blockIdx.x * 256 + threadIdx.x;
  if (e >= E) return;
  int is64 = *flag;
  int s = load_idx(ei, (size_t)e, is64);
  int d = load_idx(ei, (size_t)E + e, is64);
  int slot = row_ptr[d] + pos[e];
  float p = ea[e];
  float w1[6], w2[5];
#pragma unroll
  for (int k = 0; k < 5; ++k) {
    float sg = sig1[k], df = p - mu1[k];
    w1[k] = __expf(-0.5f / (EPS_SIGMA + sg * sg) * df * df);
  }
  {
    float sg = sigs[0], df = p - mus[0];
    w1[5] = __expf(-0.5f / (EPS_SIGMA + sg * sg) * df * df);
  }
#pragma unroll
  for (int k = 0; k < 5; ++k) {
    float sg = sig2[k], df = p - mu2[k];
    w2[k] = __expf(-0.5f / (EPS_SIGMA + sg * sg) * df * df);
  }
  wbuf1[slot] = make_uint4(pk2(w1[0], w1[1]), pk2(w1[2], w1[3]), pk2(w1[4], w1[5]), (uintT)s);
  wbuf2[slot] = make_uint4(pk2(w2[0], w2[1]), pk2(w2[2], w2[3]), pk2(w2[4], 0.f), (uintT)s);
}

// --- aggregation: wave per node; half-wave per edge; lane = 2 channels ------
template <int KT>
__device__ __forceinline__ void rec_fma2(float2* acc, uint4 r, float xlo, float xhi) {
  {
    float w = bf2f((ushortT)(r.x & 0xffffu));
    acc[0].x = fmaf(w, xlo, acc[0].x);
    acc[0].y = fmaf(w, xhi, acc[0].y);
  }
  if (KT > 1) {
    float w = bf2f((ushortT)(r.x >> 16));
    acc[1].x = fmaf(w, xlo, acc[1].x);
    acc[1].y = fmaf(w, xhi, acc[1].y);
  }
  if (KT > 2) {
    float w = bf2f((ushortT)(r.y & 0xffffu));
    acc[2].x = fmaf(w, xlo, acc[2].x);
    acc[2].y = fmaf(w, xhi, acc[2].y);
  }
  if (KT > 3) {
    float w = bf2f((ushortT)(r.y >> 16));
    acc[3].x = fmaf(w, xlo, acc[3].x);
    acc[3].y = fmaf(w, xhi, acc[3].y);
  }
  if (KT > 4) {
    float w = bf2f((ushortT)(r.z & 0xffffu));
    acc[4].x = fmaf(w, xlo, acc[4].x);
    acc[4].y = fmaf(w, xhi, acc[4].y);
  }
  if (KT > 5) {
    float w = bf2f((ushortT)(r.z >> 16));
    acc[5].x = fmaf(w, xlo, acc[5].x);
    acc[5].y = fmaf(w, xhi, acc[5].y);
  }
}

template <int KT>
__global__ __launch_bounds__(256) void agg_pre(const ushortT* __restrict__ feat,
                                               const int* __restrict__ row_ptr,
                                               const uint4* __restrict__ wbuf,
                                               ushortT* __restrict__ out, int n, int ldo) {
  int node = blockIdx.x * 4 + (threadIdx.x >> 6);
  int lane = threadIdx.x & 63;
  int h = lane >> 5;        // which edge of the pair this half-wave handles
  int l2 = lane & 31;       // channel pair index (channels 2*l2, 2*l2+1)
  if (node >= n) return;
  int beg = row_ptr[node], end = row_ptr[node + 1];
  float2 acc[KT];
#pragma unroll
  for (int k = 0; k < KT; ++k) acc[k] = make_float2(0.f, 0.f);
  int i = beg;
  // 4 pairs (8 edges) per iteration: 4 rec loads + 4 gathers in flight
  for (; i + 8 <= end; i += 8) {
    uint4 r0 = wbuf[i + 0 + h];
    uint4 r1 = wbuf[i + 2 + h];
    uint4 r2 = wbuf[i + 4 + h];
    uint4 r3 = wbuf[i + 6 + h];
    uintT x0 = *(const uintT*)&feat[((size_t)r0.w << 6) + l2 * 2];
    uintT x1 = *(const uintT*)&feat[((size_t)r1.w << 6) + l2 * 2];
    uintT x2 = *(const uintT*)&feat[((size_t)r2.w << 6) + l2 * 2];
    uintT x3 = *(const uintT*)&feat[((size_t)r3.w << 6) + l2 * 2];
    rec_fma2<KT>(acc, r0, bf2f((ushortT)(x0 & 0xffffu)), bf2f((ushortT)(x0 >> 16)));
    rec_fma2<KT>(acc, r1, bf2f((ushortT)(x1 & 0xffffu)), bf2f((ushortT)(x1 >> 16)));
    rec_fma2<KT>(acc, r2, bf2f((ushortT)(x2 & 0xffffu)), bf2f((ushortT)(x2 >> 16)));
    rec_fma2<KT>(acc, r3, bf2f((ushortT)(x3 & 0xffffu)), bf2f((ushortT)(x3 >> 16)));
  }
  // pair loop
  for (; i + 2 <= end; i += 2) {
    uint4 r = wbuf[i + h];
    uintT xb = *(const uintT*)&feat[((size_t)r.w << 6) + l2 * 2];
    rec_fma2<KT>(acc, r, bf2f((ushortT)(xb & 0xffffu)), bf2f((ushortT)(xb >> 16)));
  }
  // odd tail: only half-wave 0
  if (i < end && h == 0) {
    uint4 r = wbuf[i];
    uintT xb = *(const uintT*)&feat[((size_t)r.w << 6) + l2 * 2];
    rec_fma2<KT>(acc, r, bf2f((ushortT)(xb & 0xffffu)), bf2f((ushortT)(xb >> 16)));
  }
  int degi = end - beg;
  float invdeg = 1.0f / (float)(degi > 1 ? degi : 1);
  uintT* outu = (uintT*)out;
  size_t obase = ((size_t)node * ldo) >> 1;
#pragma unroll
  for (int k = 0; k < KT; ++k) {
    float ox = acc[k].x + __shfl_xor(acc[k].x, 32);
    float oy = acc[k].y + __shfl_xor(acc[k].y, 32);
    if (h == 0) outu[obase + k * 32 + l2] = pk2(ox * invdeg, oy * invdeg);
  }
}

// --- weight prep: Bout[(K*64+64) x 64] = [rearranged G ; root] ---------------
__global__ void prep_cat(const float* __restrict__ g, const float* __restrict__ root,
                         float* __restrict__ Bout, int K) {
  int idx = blockIdx.x * 256 + threadIdx.x;
  int total = (K + 1) * 64 * 64;
  if (idx >= total) return;
  int r = idx >> 6, c = idx & 63;
  float v;
  if (r < K * 64) {
    int k = r >> 6, i = r & 63;
    v = g[i * (K * 64) + k * 64 + c];
  } else {
    v = root[(r - K * 64) * 64 + c];
  }
  Bout[idx] = v;
}

// --- GEMM: C[M,64] = [A1(K1 bf16)|A2(64 fp32)]@B + bias ; fused BN stats ----
__global__ __launch_bounds__(256) void gemm_fused(const ushortT* __restrict__ A1, int lda1,
                                                  int K1, const float* __restrict__ A2,
                                                  const float* __restrict__ B,
                                                  const float* __restrict__ bias,
                                                  float* __restrict__ C, int M,
                                                  float* sums, float* sumsq) {
  __shared__ float As[64][68];
  __shared__ float Bs[64][64];
  __shared__ float red[16][64];
  int tile_m = blockIdx.x * 64;
  int tid = threadIdx.x, tx = tid & 15, ty = tid >> 4;
  float acc[4][4] = {};
  int nch = K1 >> 6;
  for (int ch = 0; ch <= nch; ++ch) {
    if (ch < nch) {
      int kb = ch * 64;
#pragma unroll
      for (int i = 0; i < 2; ++i) {
        int slot = tid + i * 256;          // 0..511
        int r = slot >> 3, c8 = (slot & 7) * 8;
        uint4 v = make_uint4(0u, 0u, 0u, 0u);
        if (tile_m + r < M)
          v = *(const uint4*)&A1[(size_t)(tile_m + r) * lda1 + kb + c8];
        const ushortT* us = (const ushortT*)&v;
        float f[8];
#pragma unroll
        for (int j = 0; j < 8; ++j) f[j] = bf2f(us[j]);
        *(float4*)&As[r][c8]     = make_float4(f[0], f[1], f[2], f[3]);
        *(float4*)&As[r][c8 + 4] = make_float4(f[4], f[5], f[6], f[7]);
      }
    } else {
#pragma unroll
      for (int i = 0; i < 4; ++i) {
        int idx = tid + i * 256, r = idx >> 4, c4 = idx & 15;
        float4 v = make_float4(0.f, 0.f, 0.f, 0.f);
        if (tile_m + r < M) v = *(const float4*)&A2[(size_t)(tile_m + r) * 64 + c4 * 4];
        *(float4*)&As[r][c4 * 4] = v;
      }
    }
#pragma unroll
    for (int i = 0; i < 4; ++i) {
      int idx = tid + i * 256, r = idx >> 4, c4 = idx & 15;
      *(float4*)&Bs[r][c4 * 4] = *(const float4*)&B[(size_t)(ch * 64 + r) * 64 + c4 * 4];
    }
    __syncthreads();
#pragma unroll
    for (int k = 0; k < 64; k += 4) {
      float4 b0 = *(const float4*)&Bs[k + 0][tx * 4];
      float4 b1v = *(const float4*)&Bs[k + 1][tx * 4];
      float4 b2 = *(const float4*)&Bs[k + 2][tx * 4];
      float4 b3 = *(const float4*)&Bs[k + 3][tx * 4];
#pragma unroll
      for (int i = 0; i < 4; ++i) {
        float4 a = *(const float4*)&As[ty * 4 + i][k];
        acc[i][0] = fmaf(a.x, b0.x, acc[i][0]);
        acc[i][1] = fmaf(a.x, b0.y, acc[i][1]);
        acc[i][2] = fmaf(a.x, b0.z, acc[i][2]);
        acc[i][3] = fmaf(a.x, b0.w, acc[i][3]);
        acc[i][0] = fmaf(a.y, b1v.x, acc[i][0]);
        acc[i][1] = fmaf(a.y, b1v.y, acc[i][1]);
        acc[i][2] = fmaf(a.y, b1v.z, acc[i][2]);
        acc[i][3] = fmaf(a.y, b1v.w, acc[i][3]);
        acc[i][0] = fmaf(a.z, b2.x, acc[i][0]);
        acc[i][1] = fmaf(a.z, b2.y, acc[i][1]);
        acc[i][2] = fmaf(a.z, b2.z, acc[i][2]);
        acc[i][3] = fmaf(a.z, b2.w, acc[i][3]);
        acc[i][0] = fmaf(a.w, b3.x, acc[i][0]);
        acc[i][1] = fmaf(a.w, b3.y, acc[i][1]);
        acc[i][2] = fmaf(a.w, b3.z, acc[i][2]);
        acc[i][3] = fmaf(a.w, b3.w, acc[i][3]);
      }
    }
    __syncthreads();
  }
  float cs[4] = {}, cq[4] = {};
#pragma unroll
  for (int i = 0; i < 4; ++i) {
    int r = tile_m + ty * 4 + i;
    if (r < M) {
      int cc = tx * 4;
      float ov[4];
#pragma unroll
      for (int j = 0; j < 4; ++j) {
        ov[j] = acc[i][j] + bias[cc + j];
        cs[j] += ov[j];
        cq[j] = fmaf(ov[j], ov[j], cq[j]);
      }
      *(float4*)&C[(size_t)r * 64 + cc] = make_float4(ov[0], ov[1], ov[2], ov[3]);
    }
  }
#pragma unroll
  for (int j = 0; j < 4; ++j) red[ty][tx * 4 + j] = cs[j];
  __syncthreads();
  if (tid < 64) {
    float t = 0.f;
#pragma unroll
    for (int g = 0; g < 16; ++g) t += red[g][tid];
    atomicAdd(&sums[tid], t);
  }
  __syncthreads();
#pragma unroll
  for (int j = 0; j < 4; ++j) red[ty][tx * 4 + j] = cq[j];
  __syncthreads();
  if (tid < 64) {
    float t = 0.f;
#pragma unroll
    for (int g = 0; g < 16; ++g) t += red[g][tid];
    atomicAdd(&sumsq[tid], t);
  }
}

// --- batchnorm scale/shift + epilogues --------------------------------------
__global__ void bn_final(const float* sum, const float* sumsq, const float* gamma,
                         const float* beta, int n, float* scale, float* shift) {
  int c = threadIdx.x;
  float m = sum[c] / (float)n;
  float v = sumsq[c] / (float)n - m * m;
  float r = rsqrtf(v + BN_EPS);
  float s = r * gamma[c];
  scale[c] = s;
  shift[c] = beta[c] - m * s;
}

// normalize + ELU; writes fp32 (GEMM A2 operand) and bf16 (agg gather feed)
__global__ void norm_elu(float* h, ushortT* __restrict__ h_bf,
                         const float* __restrict__ scale,
                         const float* __restrict__ shift, int total) {
  int i = blockIdx.x * 256 + threadIdx.x;
  if (i >= total) return;
  int c = i & 63;
  float v = h[i] * scale[c] + shift[c];
  v = v > 0.f ? v : expm1f(v);
  h[i] = v;
  h_bf[i] = f2bf(v);
}

__global__ void final_kernel(const float* __restrict__ h2, const float* __restrict__ sc,
                             const float* __restrict__ s2, const float* __restrict__ t2,
                             const float* __restrict__ ss, const float* __restrict__ ts,
                             float* __restrict__ out, int total) {
  int i = blockIdx.x * 256 + threadIdx.x;
  if (i >= total) return;
  int c = i & 63;
  float v = h2[i] * s2[c] + t2[c] + sc[i] * ss[c] + ts[c];
  out[i] = v > 0.f ? v : expm1f(v);
}

// ---------------------------------------------------------------------------
extern "C" void kernel_launch(void* const* d_in, const int* in_sizes, int n_in,
                              void* d_out, int out_size, void* d_ws, size_t ws_size,
                              hipStream_t stream) {
  const float* x    = (const float*)d_in[0];
  const void*  ei   = d_in[1];
  const float* ea   = (const float*)d_in[2];
  const float* g1   = (const float*)d_in[3];
  const float* mu1  = (const float*)d_in[4];
  const float* sig1 = (const float*)d_in[5];
  const float* root1= (const float*)d_in[6];
  const float* b1   = (const float*)d_in[7];
  const float* gam1 = (const float*)d_in[8];
  const float* bet1 = (const float*)d_in[9];
  const float* g2   = (const float*)d_in[10];
  const float* mu2  = (const float*)d_in[11];
  const float* sig2 = (const float*)d_in[12];
  const float* root2= (const float*)d_in[13];
  const float* b2   = (const float*)d_in[14];
  const float* gam2 = (const float*)d_in[15];
  const float* bet2 = (const float*)d_in[16];
  const float* gs   = (const float*)d_in[17];
  const float* mus  = (const float*)d_in[18];
  const float* sigs = (const float*)d_in[19];
  const float* roots= (const float*)d_in[20];
  const float* bs   = (const float*)d_in[21];
  const float* gams = (const float*)d_in[22];
  const float* bets = (const float*)d_in[23];

  int N = in_sizes[0] / 64;
  int E = in_sizes[1] / 2;

  char* w = (char*)d_ws;
  auto alloc = [&](size_t bytes) {
    char* p = w;
    w += (bytes + 255) & ~(size_t)255;
    return p;
  };
  int*     flag    = (int*)alloc(256);
  int*     cnt     = (int*)alloc((size_t)N * 4);
  int*     row_ptr = (int*)alloc((size_t)(N + 1) * 4);
  int*     partials= (int*)alloc(256 * 4);
  int*     pos     = (int*)alloc((size_t)E * 4);
  uint4*   wbuf1   = (uint4*)alloc((size_t)E * 16);       // layer1+sc records
  uint4*   wbuf2   = (uint4*)alloc((size_t)E * 16);       // layer2 records
  ushortT* Abuf    = (ushortT*)alloc((size_t)N * 384 * 2); // agg outputs (bf16)
  ushortT* x_bf    = (ushortT*)alloc((size_t)N * 64 * 2);
  ushortT* h_bf    = (ushortT*)alloc((size_t)N * 64 * 2);
  float*   h       = (float*)alloc((size_t)N * 64 * 4);
  float*   h2      = (float*)alloc((size_t)N * 64 * 4);
  float*   scb     = (float*)alloc((size_t)N * 64 * 4);
  float*   B1cat   = (float*)alloc(384 * 64 * 4);
  float*   B2cat   = (float*)alloc(384 * 64 * 4);
  float*   Bsc     = (float*)alloc(128 * 64 * 4);
  float*   stats   = (float*)alloc(12 * 64 * 4);

  hipMemsetAsync(cnt, 0, (size_t)N * 4, stream);
  hipMemsetAsync(stats, 0, 12 * 64 * 4, stream);

  int eb = (E + 255) / 256;
  int nb1 = (N + 2047) / 2048;
  int nb_elem = (N * 64 + 255) / 256;

  prep_cat<<<(6 * 4096 + 255) / 256, 256, 0, stream>>>(g1, root1, B1cat, 5);
  prep_cat<<<(6 * 4096 + 255) / 256, 256, 0, stream>>>(g2, root2, B2cat, 5);
  prep_cat<<<(2 * 4096 + 255) / 256, 256, 0, stream>>>(gs, roots, Bsc, 1);
  to_bf16<<<(N * 64 / 4 + 255) / 256, 256, 0, stream>>>(x, x_bf, N * 64);

  detect_kernel<<<1, 256, 0, stream>>>(ei, flag);
  hist_kernel<<<eb, 256, 0, stream>>>(ei, E, flag, cnt, pos);
  scan1<<<nb1, 256, 0, stream>>>(cnt, row_ptr, partials, N);
  scan2<<<1, 256, 0, stream>>>(partials, nb1, row_ptr, N);
  scan3<<<(N + 255) / 256, 256, 0, stream>>>(row_ptr, partials, N);
  scatter_wgt<<<eb, 256, 0, stream>>>(ei, ea, E, flag, row_ptr, pos,
                                      mu1, sig1, mus, sigs, mu2, sig2, wbuf1, wbuf2);

  int mtiles = (N + 63) / 64;
  int nb_node = (N + 3) / 4;

  // ---- layer1 + shortcut ----
  agg_pre<6><<<nb_node, 256, 0, stream>>>(x_bf, row_ptr, wbuf1, Abuf, N, 384);
  gemm_fused<<<mtiles, 256, 0, stream>>>(Abuf, 384, 320, x, B1cat, b1, h, N,
                                         stats + 0 * 64, stats + 1 * 64);
  gemm_fused<<<mtiles, 256, 0, stream>>>(Abuf + 320, 384, 64, x, Bsc, bs, scb, N,
                                         stats + 4 * 64, stats + 5 * 64);
  bn_final<<<1, 64, 0, stream>>>(stats + 0 * 64, stats + 1 * 64, gam1, bet1, N,
                                 stats + 6 * 64, stats + 7 * 64);
  norm_elu<<<nb_elem, 256, 0, stream>>>(h, h_bf, stats + 6 * 64, stats + 7 * 64, N * 64);

  // ---- layer2 ----
  agg_pre<5><<<nb_node, 256, 0, stream>>>(h_bf, row_ptr, wbuf2, Abuf, N, 320);
  gemm_fused<<<mtiles, 256, 0, stream>>>(Abuf, 320, 320, h, B2cat, b2, h2, N,
                                         stats + 2 * 64, stats + 3 * 64);

  bn_final<<<1, 64, 0, stream>>>(stats + 2 * 64, stats + 3 * 64, gam2, bet2, N,
                                 stats + 8 * 64, stats + 9 * 64);
  bn_final<<<1, 64, 0, stream>>>(stats + 4 * 64, stats + 5 * 64, gams, bets, N,
                                 stats + 10 * 64, stats + 11 * 64);

  final_kernel<<<nb_elem, 256, 0, stream>>>(h2, scb, stats + 8 * 64, stats + 9 * 64,
                                            stats + 10 * 64, stats + 11 * 64,
                                            (float*)d_out, N * 64);
}

// Round 10
// 277.662 us; speedup vs baseline: 1.4611x; 1.1832x over previous
//
#include <hip/hip_runtime.h>
#include <hip/hip_bf16.h>

// ---------------------------------------------------------------------------
// ResidualBlock: GMMConv(x)->BN->ELU->GMMConv->BN  +  GMMConv_sc(x)->BN ; ELU
// N=50000, E=800000, C=64, K_main=5, K_sc=1.
// Round 10: GEMM moved to MFMA (v_mfma_f32_16x16x32_bf16). A operands are
// already bf16 (Abuf/x_bf/h_bf); B pre-packed to fragment layout in bf16.
// No LDS staging (A frag = one 16B global load/lane; B frag coalesced).
// Kills round-9 gemm's 500K bank conflicts + 84 VGPR + 18% occupancy.
// agg/scatter/CSR from round 9 unchanged.
// ---------------------------------------------------------------------------

#define EPS_SIGMA 1e-15f
#define BN_EPS    1e-5f

typedef unsigned short ushortT;
typedef unsigned int uintT;
typedef __attribute__((ext_vector_type(8))) short bf16x8;
typedef __attribute__((ext_vector_type(4))) float f32x4;

__device__ __forceinline__ ushortT f2bf(float f) {
  uintT b = __float_as_uint(f);
  b += 0x7FFFu + ((b >> 16) & 1u);   // round-to-nearest-even
  return (ushortT)(b >> 16);
}
__device__ __forceinline__ float bf2f(ushortT u) {
  return __uint_as_float(((uintT)u) << 16);
}
__device__ __forceinline__ uintT pk2(float a, float b) {
  return (uintT)f2bf(a) | ((uintT)f2bf(b) << 16);
}

// --- dtype detect: int64 edge_index has all-zero high words -----------------
__global__ void detect_kernel(const void* ei, int* flag) {
  const int* p = (const int*)ei;
  __shared__ int bad;
  if (threadIdx.x == 0) bad = 0;
  __syncthreads();
  if (p[threadIdx.x * 2 + 1] != 0) atomicAdd(&bad, 1);
  __syncthreads();
  if (threadIdx.x == 0) *flag = (bad == 0);  // 1 => int64 layout
}

__device__ __forceinline__ int load_idx(const void* ei, size_t pos, int is64) {
  if (is64) return (int)((const long long*)ei)[pos];
  return ((const int*)ei)[pos];
}

// --- fp32 -> bf16 convert (vectorized) --------------------------------------
__global__ void to_bf16(const float* __restrict__ in, ushortT* __restrict__ out, int total) {
  int idx = (blockIdx.x * 256 + threadIdx.x) * 4;
  if (idx + 3 < total) {
    float4 v = *(const float4*)&in[idx];
    ushortT o[4] = {f2bf(v.x), f2bf(v.y), f2bf(v.z), f2bf(v.w)};
    *(uint2*)&out[idx] = *(const uint2*)o;
  } else {
    for (int j = 0; j < 4 && idx + j < total; ++j) out[idx + j] = f2bf(in[idx + j]);
  }
}

// --- CSR build: hist also records each edge's within-bucket position --------
__global__ void hist_kernel(const void* ei, int E, const int* flag, int* cnt,
                            int* __restrict__ pos) {
  int e = blockIdx.x * blockDim.x + threadIdx.x;
  if (e >= E) return;
  int d = load_idx(ei, (size_t)E + e, *flag);
  pos[e] = atomicAdd(&cnt[d], 1);
}

__global__ __launch_bounds__(256) void scan1(const int* __restrict__ cnt,
                                             int* __restrict__ row_ptr,
                                             int* __restrict__ partials, int n) {
  int tid = threadIdx.x;
  int base = blockIdx.x * 2048 + tid * 8;
  int v[8], pre[8];
  int run = 0;
#pragma unroll
  for (int j = 0; j < 8; ++j) {
    int idx = base + j;
    v[j] = (idx < n) ? cnt[idx] : 0;
    pre[j] = run;
    run += v[j];
  }
  __shared__ int sd[256];
  sd[tid] = run;
  __syncthreads();
  for (int off = 1; off < 256; off <<= 1) {
    int t = (tid >= off) ? sd[tid - off] : 0;
    __syncthreads();
    sd[tid] += t;
    __syncthreads();
  }
  int excl = sd[tid] - run;
#pragma unroll
  for (int j = 0; j < 8; ++j) {
    int idx = base + j;
    if (idx < n) row_ptr[idx] = excl + pre[j];
  }
  if (tid == 255) partials[blockIdx.x] = sd[255];
}

__global__ void scan2(int* partials, int nb, int* row_ptr, int n) {
  __shared__ int sd[256];
  int tid = threadIdx.x;
  int v = (tid < nb) ? partials[tid] : 0;
  sd[tid] = v;
  __syncthreads();
  for (int off = 1; off < 256; off <<= 1) {
    int t = (tid >= off) ? sd[tid - off] : 0;
    __syncthreads();
    sd[tid] += t;
    __syncthreads();
  }
  if (tid < nb) partials[tid] = sd[tid] - v;
  if (tid == nb - 1) row_ptr[n] = sd[tid];
}

__global__ void scan3(int* __restrict__ row_ptr, const int* __restrict__ partials, int n) {
  int i = blockIdx.x * 256 + threadIdx.x;
  if (i < n) row_ptr[i] += partials[i >> 11];
}

// --- scatter + gaussian weights: ONE 16B record per edge per layer ----------
__global__ __launch_bounds__(256) void scatter_wgt(
    const void* ei, const float* __restrict__ ea, int E, const int* flag,
    const int* __restrict__ row_ptr, const int* __restrict__ pos,
    const float* __restrict__ mu1, const float* __restrict__ sig1,
    const float* __restrict__ mus, const float* __restrict__ sigs,
    const float* __restrict__ mu2, const float* __restrict__ sig2,
    uint4* __restrict__ wbuf1, uint4* __restrict__ wbuf2) {
  int e = blockIdx.x * 256 + threadIdx.x;
  if (e >= E) return;
  int is64 = *flag;
  int s = load_idx(ei, (size_t)e, is64);
  int d = load_idx(ei, (size_t)E + e, is64);
  int slot = row_ptr[d] + pos[e];
  float p = ea[e];
  float w1[6], w2[5];
#pragma unroll
  for (int k = 0; k < 5; ++k) {
    float sg = sig1[k], df = p - mu1[k];
    w1[k] = __expf(-0.5f / (EPS_SIGMA + sg * sg) * df * df);
  }
  {
    float sg = sigs[0], df = p - mus[0];
    w1[5] = __expf(-0.5f / (EPS_SIGMA + sg * sg) * df * df);
  }
#pragma unroll
  for (int k = 0; k < 5; ++k) {
    float sg = sig2[k], df = p - mu2[k];
    w2[k] = __expf(-0.5f / (EPS_SIGMA + sg * sg) * df * df);
  }
  wbuf1[slot] = make_uint4(pk2(w1[0], w1[1]), pk2(w1[2], w1[3]), pk2(w1[4], w1[5]), (uintT)s);
  wbuf2[slot] = make_uint4(pk2(w2[0], w2[1]), pk2(w2[2], w2[3]), pk2(w2[4], 0.f), (uintT)s);
}

// --- aggregation: wave per node; half-wave per edge; lane = 2 channels ------
template <int KT>
__device__ __forceinline__ void rec_fma2(float2* acc, uint4 r, float xlo, float xhi) {
  {
    float w = bf2f((ushortT)(r.x & 0xffffu));
    acc[0].x = fmaf(w, xlo, acc[0].x);
    acc[0].y = fmaf(w, xhi, acc[0].y);
  }
  if (KT > 1) {
    float w = bf2f((ushortT)(r.x >> 16));
    acc[1].x = fmaf(w, xlo, acc[1].x);
    acc[1].y = fmaf(w, xhi, acc[1].y);
  }
  if (KT > 2) {
    float w = bf2f((ushortT)(r.y & 0xffffu));
    acc[2].x = fmaf(w, xlo, acc[2].x);
    acc[2].y = fmaf(w, xhi, acc[2].y);
  }
  if (KT > 3) {
    float w = bf2f((ushortT)(r.y >> 16));
    acc[3].x = fmaf(w, xlo, acc[3].x);
    acc[3].y = fmaf(w, xhi, acc[3].y);
  }
  if (KT > 4) {
    float w = bf2f((ushortT)(r.z & 0xffffu));
    acc[4].x = fmaf(w, xlo, acc[4].x);
    acc[4].y = fmaf(w, xhi, acc[4].y);
  }
  if (KT > 5) {
    float w = bf2f((ushortT)(r.z >> 16));
    acc[5].x = fmaf(w, xlo, acc[5].x);
    acc[5].y = fmaf(w, xhi, acc[5].y);
  }
}

template <int KT>
__global__ __launch_bounds__(256) void agg_pre(const ushortT* __restrict__ feat,
                                               const int* __restrict__ row_ptr,
                                               const uint4* __restrict__ wbuf,
                                               ushortT* __restrict__ out, int n, int ldo) {
  int node = blockIdx.x * 4 + (threadIdx.x >> 6);
  int lane = threadIdx.x & 63;
  int h = lane >> 5;
  int l2 = lane & 31;
  if (node >= n) return;
  int beg = row_ptr[node], end = row_ptr[node + 1];
  float2 acc[KT];
#pragma unroll
  for (int k = 0; k < KT; ++k) acc[k] = make_float2(0.f, 0.f);
  int i = beg;
  for (; i + 8 <= end; i += 8) {
    uint4 r0 = wbuf[i + 0 + h];
    uint4 r1 = wbuf[i + 2 + h];
    uint4 r2 = wbuf[i + 4 + h];
    uint4 r3 = wbuf[i + 6 + h];
    uintT x0 = *(const uintT*)&feat[((size_t)r0.w << 6) + l2 * 2];
    uintT x1 = *(const uintT*)&feat[((size_t)r1.w << 6) + l2 * 2];
    uintT x2 = *(const uintT*)&feat[((size_t)r2.w << 6) + l2 * 2];
    uintT x3 = *(const uintT*)&feat[((size_t)r3.w << 6) + l2 * 2];
    rec_fma2<KT>(acc, r0, bf2f((ushortT)(x0 & 0xffffu)), bf2f((ushortT)(x0 >> 16)));
    rec_fma2<KT>(acc, r1, bf2f((ushortT)(x1 & 0xffffu)), bf2f((ushortT)(x1 >> 16)));
    rec_fma2<KT>(acc, r2, bf2f((ushortT)(x2 & 0xffffu)), bf2f((ushortT)(x2 >> 16)));
    rec_fma2<KT>(acc, r3, bf2f((ushortT)(x3 & 0xffffu)), bf2f((ushortT)(x3 >> 16)));
  }
  for (; i + 2 <= end; i += 2) {
    uint4 r = wbuf[i + h];
    uintT xb = *(const uintT*)&feat[((size_t)r.w << 6) + l2 * 2];
    rec_fma2<KT>(acc, r, bf2f((ushortT)(xb & 0xffffu)), bf2f((ushortT)(xb >> 16)));
  }
  if (i < end && h == 0) {
    uint4 r = wbuf[i];
    uintT xb = *(const uintT*)&feat[((size_t)r.w << 6) + l2 * 2];
    rec_fma2<KT>(acc, r, bf2f((ushortT)(xb & 0xffffu)), bf2f((ushortT)(xb >> 16)));
  }
  int degi = end - beg;
  float invdeg = 1.0f / (float)(degi > 1 ? degi : 1);
  uintT* outu = (uintT*)out;
  size_t obase = ((size_t)node * ldo) >> 1;
#pragma unroll
  for (int k = 0; k < KT; ++k) {
    float ox = acc[k].x + __shfl_xor(acc[k].x, 32);
    float oy = acc[k].y + __shfl_xor(acc[k].y, 32);
    if (h == 0) outu[obase + k * 32 + l2] = pk2(ox * invdeg, oy * invdeg);
  }
}

// --- B prep: pack [G_rearranged ; root] into MFMA B-fragment layout (bf16) --
// Bfull[r][c]: r<K*64 -> g[i*(K*64)+k*64+c] (k=r>>6,i=r&63); else root[(r-K*64)*64+c]
// Bm[((ks*4+nt)*64+lane)*8 + j] = Bfull[ks*32 + (lane>>4)*8 + j][nt*16 + (lane&15)]
__global__ void prep_bm(const float* __restrict__ g, const float* __restrict__ root,
                        ushortT* __restrict__ Bm, int K, int nks) {
  int t = blockIdx.x * 256 + threadIdx.x;
  if (t >= nks * 256) return;
  int ks = t >> 8, rem = t & 255;
  int nt = rem >> 6, lane = rem & 63;
  int kbase = ks * 32 + (lane >> 4) * 8;
  int col = nt * 16 + (lane & 15);
  ushortT o[8];
#pragma unroll
  for (int j = 0; j < 8; ++j) {
    int r = kbase + j;
    float v;
    if (r < K * 64) {
      int k = r >> 6, i = r & 63;
      v = g[(size_t)i * (K * 64) + k * 64 + col];
    } else {
      v = root[(size_t)(r - K * 64) * 64 + col];
    }
    o[j] = f2bf(v);
  }
  *(uint4*)&Bm[(size_t)t * 8] = *(const uint4*)o;
}

// --- MFMA GEMM: C[M,64] = [A1(K1 bf16)|A2(64 bf16)]@B + bias ; BN stats -----
// 4 waves/block, wave = 16 rows x 64 cols, no LDS staging.
__global__ __launch_bounds__(256) void gemm_mfma(const ushortT* __restrict__ A1, int lda1,
                                                 int K1, const ushortT* __restrict__ A2,
                                                 const ushortT* __restrict__ Bm,
                                                 const float* __restrict__ bias,
                                                 float* __restrict__ C, int M,
                                                 float* sums, float* sumsq) {
  __shared__ float red_s[4][64];
  __shared__ float red_q[4][64];
  int tid = threadIdx.x;
  int wid = tid >> 6, lane = tid & 63;
  int row16 = lane & 15, kg = lane >> 4;        // A-row in tile / k-group
  int rowbase = blockIdx.x * 64 + wid * 16;
  int arow = rowbase + row16;
  if (arow >= M) arow = M - 1;                  // clamp; garbage feeds masked rows only
  const ushortT* a1p = A1 + (size_t)arow * lda1 + kg * 8;
  const ushortT* a2p = A2 + (size_t)arow * 64 + kg * 8;
  int nks1 = K1 >> 5;
  int nks = (K1 + 64) >> 5;
  f32x4 acc[4];
#pragma unroll
  for (int nt = 0; nt < 4; ++nt) acc[nt] = (f32x4){0.f, 0.f, 0.f, 0.f};
  for (int ks = 0; ks < nks; ++ks) {
    const ushortT* ap = (ks < nks1) ? (a1p + ks * 32) : (a2p + (ks - nks1) * 32);
    bf16x8 af = *(const bf16x8*)ap;
#pragma unroll
    for (int nt = 0; nt < 4; ++nt) {
      bf16x8 bfr = *(const bf16x8*)(Bm + (size_t)ks * 2048 + nt * 512 + lane * 8);
      acc[nt] = __builtin_amdgcn_mfma_f32_16x16x32_bf16(af, bfr, acc[nt], 0, 0, 0);
    }
  }
  // D layout: row = kg*4 + r, col = nt*16 + row16
  float bv[4];
#pragma unroll
  for (int nt = 0; nt < 4; ++nt) bv[nt] = bias[nt * 16 + row16];
  float cs[4] = {}, cq[4] = {};
#pragma unroll
  for (int r = 0; r < 4; ++r) {
    int orow = rowbase + kg * 4 + r;
    if (orow < M) {
#pragma unroll
      for (int nt = 0; nt < 4; ++nt) {
        float v = acc[nt][r] + bv[nt];
        C[(size_t)orow * 64 + nt * 16 + row16] = v;
        cs[nt] += v;
        cq[nt] = fmaf(v, v, cq[nt]);
      }
    }
  }
  // reduce across the 4 kg groups (lanes differing in bits 4,5)
#pragma unroll
  for (int nt = 0; nt < 4; ++nt) {
    cs[nt] += __shfl_xor(cs[nt], 16);
    cs[nt] += __shfl_xor(cs[nt], 32);
    cq[nt] += __shfl_xor(cq[nt], 16);
    cq[nt] += __shfl_xor(cq[nt], 32);
  }
  if (lane < 16) {
#pragma unroll
    for (int nt = 0; nt < 4; ++nt) {
      red_s[wid][nt * 16 + lane] = cs[nt];
      red_q[wid][nt * 16 + lane] = cq[nt];
    }
  }
  __syncthreads();
  if (tid < 64) {
    float ts = red_s[0][tid] + red_s[1][tid] + red_s[2][tid] + red_s[3][tid];
    float tq = red_q[0][tid] + red_q[1][tid] + red_q[2][tid] + red_q[3][tid];
    atomicAdd(&sums[tid], ts);
    atomicAdd(&sumsq[tid], tq);
  }
}

// --- batchnorm scale/shift + epilogues --------------------------------------
__global__ void bn_final(const float* sum, const float* sumsq, const float* gamma,
                         const float* beta, int n, float* scale, float* shift) {
  int c = threadIdx.x;
  float m = sum[c] / (float)n;
  float v = sumsq[c] / (float)n - m * m;
  float r = rsqrtf(v + BN_EPS);
  float s = r * gamma[c];
  scale[c] = s;
  shift[c] = beta[c] - m * s;
}

// normalize + ELU; writes fp32 and bf16 copies
__global__ void norm_elu(float* h, ushortT* __restrict__ h_bf,
                         const float* __restrict__ scale,
                         const float* __restrict__ shift, int total) {
  int i = blockIdx.x * 256 + threadIdx.x;
  if (i >= total) return;
  int c = i & 63;
  float v = h[i] * scale[c] + shift[c];
  v = v > 0.f ? v : expm1f(v);
  h[i] = v;
  h_bf[i] = f2bf(v);
}

__global__ void final_kernel(const float* __restrict__ h2, const float* __restrict__ sc,
                             const float* __restrict__ s2, const float* __restrict__ t2,
                             const float* __restrict__ ss, const float* __restrict__ ts,
                             float* __restrict__ out, int total) {
  int i = blockIdx.x * 256 + threadIdx.x;
  if (i >= total) return;
  int c = i & 63;
  float v = h2[i] * s2[c] + t2[c] + sc[i] * ss[c] + ts[c];
  out[i] = v > 0.f ? v : expm1f(v);
}

// ---------------------------------------------------------------------------
extern "C" void kernel_launch(void* const* d_in, const int* in_sizes, int n_in,
                              void* d_out, int out_size, void* d_ws, size_t ws_size,
                              hipStream_t stream) {
  const float* x    = (const float*)d_in[0];
  const void*  ei   = d_in[1];
  const float* ea   = (const float*)d_in[2];
  const float* g1   = (const float*)d_in[3];
  const float* mu1  = (const float*)d_in[4];
  const float* sig1 = (const float*)d_in[5];
  const float* root1= (const float*)d_in[6];
  const float* b1   = (const float*)d_in[7];
  const float* gam1 = (const float*)d_in[8];
  const float* bet1 = (const float*)d_in[9];
  const float* g2   = (const float*)d_in[10];
  const float* mu2  = (const float*)d_in[11];
  const float* sig2 = (const float*)d_in[12];
  const float* root2= (const float*)d_in[13];
  const float* b2   = (const float*)d_in[14];
  const float* gam2 = (const float*)d_in[15];
  const float* bet2 = (const float*)d_in[16];
  const float* gs   = (const float*)d_in[17];
  const float* mus  = (const float*)d_in[18];
  const float* sigs = (const float*)d_in[19];
  const float* roots= (const float*)d_in[20];
  const float* bs   = (const float*)d_in[21];
  const float* gams = (const float*)d_in[22];
  const float* bets = (const float*)d_in[23];

  int N = in_sizes[0] / 64;
  int E = in_sizes[1] / 2;

  char* w = (char*)d_ws;
  auto alloc = [&](size_t bytes) {
    char* p = w;
    w += (bytes + 255) & ~(size_t)255;
    return p;
  };
  int*     flag    = (int*)alloc(256);
  int*     cnt     = (int*)alloc((size_t)N * 4);
  int*     row_ptr = (int*)alloc((size_t)(N + 1) * 4);
  int*     partials= (int*)alloc(256 * 4);
  int*     pos     = (int*)alloc((size_t)E * 4);
  uint4*   wbuf1   = (uint4*)alloc((size_t)E * 16);        // layer1+sc records
  uint4*   wbuf2   = (uint4*)alloc((size_t)E * 16);        // layer2 records
  ushortT* Abuf    = (ushortT*)alloc((size_t)N * 384 * 2); // agg outputs (bf16)
  ushortT* x_bf    = (ushortT*)alloc((size_t)N * 64 * 2);
  ushortT* h_bf    = (ushortT*)alloc((size_t)N * 64 * 2);
  float*   h       = (float*)alloc((size_t)N * 64 * 4);
  float*   h2      = (float*)alloc((size_t)N * 64 * 4);
  float*   scb     = (float*)alloc((size_t)N * 64 * 4);
  ushortT* Bm1     = (ushortT*)alloc(12 * 2048 * 2);       // MFMA-layout B (bf16)
  ushortT* Bm2     = (ushortT*)alloc(12 * 2048 * 2);
  ushortT* Bmsc    = (ushortT*)alloc(4 * 2048 * 2);
  float*   stats   = (float*)alloc(12 * 64 * 4);

  hipMemsetAsync(cnt, 0, (size_t)N * 4, stream);
  hipMemsetAsync(stats, 0, 12 * 64 * 4, stream);

  int eb = (E + 255) / 256;
  int nb1 = (N + 2047) / 2048;
  int nb_elem = (N * 64 + 255) / 256;

  prep_bm<<<12, 256, 0, stream>>>(g1, root1, Bm1, 5, 12);
  prep_bm<<<12, 256, 0, stream>>>(g2, root2, Bm2, 5, 12);
  prep_bm<<<4, 256, 0, stream>>>(gs, roots, Bmsc, 1, 4);
  to_bf16<<<(N * 64 / 4 + 255) / 256, 256, 0, stream>>>(x, x_bf, N * 64);

  detect_kernel<<<1, 256, 0, stream>>>(ei, flag);
  hist_kernel<<<eb, 256, 0, stream>>>(ei, E, flag, cnt, pos);
  scan1<<<nb1, 256, 0, stream>>>(cnt, row_ptr, partials, N);
  scan2<<<1, 256, 0, stream>>>(partials, nb1, row_ptr, N);
  scan3<<<(N + 255) / 256, 256, 0, stream>>>(row_ptr, partials, N);
  scatter_wgt<<<eb, 256, 0, stream>>>(ei, ea, E, flag, row_ptr, pos,
                                      mu1, sig1, mus, sigs, mu2, sig2, wbuf1, wbuf2);

  int mtiles = (N + 63) / 64;
  int nb_node = (N + 3) / 4;

  // ---- layer1 + shortcut ----
  agg_pre<6><<<nb_node, 256, 0, stream>>>(x_bf, row_ptr, wbuf1, Abuf, N, 384);
  gemm_mfma<<<mtiles, 256, 0, stream>>>(Abuf, 384, 320, x_bf, Bm1, b1, h, N,
                                        stats + 0 * 64, stats + 1 * 64);
  gemm_mfma<<<mtiles, 256, 0, stream>>>(Abuf + 320, 384, 64, x_bf, Bmsc, bs, scb, N,
                                        stats + 4 * 64, stats + 5 * 64);
  bn_final<<<1, 64, 0, stream>>>(stats + 0 * 64, stats + 1 * 64, gam1, bet1, N,
                                 stats + 6 * 64, stats + 7 * 64);
  norm_elu<<<nb_elem, 256, 0, stream>>>(h, h_bf, stats + 6 * 64, stats + 7 * 64, N * 64);

  // ---- layer2 ----
  agg_pre<5><<<nb_node, 256, 0, stream>>>(h_bf, row_ptr, wbuf2, Abuf, N, 320);
  gemm_mfma<<<mtiles, 256, 0, stream>>>(Abuf, 320, 320, h_bf, Bm2, b2, h2, N,
                                        stats + 2 * 64, stats + 3 * 64);

  bn_final<<<1, 64, 0, stream>>>(stats + 2 * 64, stats + 3 * 64, gam2, bet2, N,
                                 stats + 8 * 64, stats + 9 * 64);
  bn_final<<<1, 64, 0, stream>>>(stats + 4 * 64, stats + 5 * 64, gams, bets, N,
                                 stats + 10 * 64, stats + 11 * 64);

  final_kernel<<<nb_elem, 256, 0, stream>>>(h2, scb, stats + 8 * 64, stats + 9 * 64,
                                            stats + 10 * 64, stats + 11 * 64,
                                            (float*)d_out, N * 64);
}

// Round 11
// 251.985 us; speedup vs baseline: 1.6100x; 1.1019x over previous
//
#include <hip/hip_runtime.h>
#include <hip/hip_bf16.h>

// ---------------------------------------------------------------------------
// ResidualBlock: GMMConv(x)->BN->ELU->GMMConv->BN  +  GMMConv_sc(x)->BN ; ELU
// N=50000, E=800000, C=64, K_main=5, K_sc=1.
// Round 11: hipMemsetAsync graph nodes cost ~41us EACH (rocprof: fillBuffer
// 41us, WRITE_SIZE=3KB = stats buf) -> replaced with zero_ws kernel (~3us).
// Layer1+shortcut GEMMs merged into one dual-MFMA kernel (share x_bf A2;
// 14 A-frag loads vs 16, one epilogue saved). MFMA acc is lean (16 VGPR per
// output) so no round-3-style spill. Rest unchanged from round 10.
// ---------------------------------------------------------------------------

#define EPS_SIGMA 1e-15f
#define BN_EPS    1e-5f

typedef unsigned short ushortT;
typedef unsigned int uintT;
typedef __attribute__((ext_vector_type(8))) short bf16x8;
typedef __attribute__((ext_vector_type(4))) float f32x4;

__device__ __forceinline__ ushortT f2bf(float f) {
  uintT b = __float_as_uint(f);
  b += 0x7FFFu + ((b >> 16) & 1u);   // round-to-nearest-even
  return (ushortT)(b >> 16);
}
__device__ __forceinline__ float bf2f(ushortT u) {
  return __uint_as_float(((uintT)u) << 16);
}
__device__ __forceinline__ uintT pk2(float a, float b) {
  return (uintT)f2bf(a) | ((uintT)f2bf(b) << 16);
}

// --- workspace zeroing (replaces hipMemsetAsync graph nodes) ----------------
__global__ void zero_ws(int* __restrict__ cnt, float* __restrict__ stats, int n) {
  int i = blockIdx.x * 256 + threadIdx.x;
  if (i < n) cnt[i] = 0;
  if (i < 12 * 64) stats[i] = 0.f;
}

// --- dtype detect: int64 edge_index has all-zero high words -----------------
__global__ void detect_kernel(const void* ei, int* flag) {
  const int* p = (const int*)ei;
  __shared__ int bad;
  if (threadIdx.x == 0) bad = 0;
  __syncthreads();
  if (p[threadIdx.x * 2 + 1] != 0) atomicAdd(&bad, 1);
  __syncthreads();
  if (threadIdx.x == 0) *flag = (bad == 0);  // 1 => int64 layout
}

__device__ __forceinline__ int load_idx(const void* ei, size_t pos, int is64) {
  if (is64) return (int)((const long long*)ei)[pos];
  return ((const int*)ei)[pos];
}

// --- fp32 -> bf16 convert (vectorized) --------------------------------------
__global__ void to_bf16(const float* __restrict__ in, ushortT* __restrict__ out, int total) {
  int idx = (blockIdx.x * 256 + threadIdx.x) * 4;
  if (idx + 3 < total) {
    float4 v = *(const float4*)&in[idx];
    ushortT o[4] = {f2bf(v.x), f2bf(v.y), f2bf(v.z), f2bf(v.w)};
    *(uint2*)&out[idx] = *(const uint2*)o;
  } else {
    for (int j = 0; j < 4 && idx + j < total; ++j) out[idx + j] = f2bf(in[idx + j]);
  }
}

// --- CSR build: hist also records each edge's within-bucket position --------
__global__ void hist_kernel(const void* ei, int E, const int* flag, int* cnt,
                            int* __restrict__ pos) {
  int e = blockIdx.x * blockDim.x + threadIdx.x;
  if (e >= E) return;
  int d = load_idx(ei, (size_t)E + e, *flag);
  pos[e] = atomicAdd(&cnt[d], 1);
}

__global__ __launch_bounds__(256) void scan1(const int* __restrict__ cnt,
                                             int* __restrict__ row_ptr,
                                             int* __restrict__ partials, int n) {
  int tid = threadIdx.x;
  int base = blockIdx.x * 2048 + tid * 8;
  int v[8], pre[8];
  int run = 0;
#pragma unroll
  for (int j = 0; j < 8; ++j) {
    int idx = base + j;
    v[j] = (idx < n) ? cnt[idx] : 0;
    pre[j] = run;
    run += v[j];
  }
  __shared__ int sd[256];
  sd[tid] = run;
  __syncthreads();
  for (int off = 1; off < 256; off <<= 1) {
    int t = (tid >= off) ? sd[tid - off] : 0;
    __syncthreads();
    sd[tid] += t;
    __syncthreads();
  }
  int excl = sd[tid] - run;
#pragma unroll
  for (int j = 0; j < 8; ++j) {
    int idx = base + j;
    if (idx < n) row_ptr[idx] = excl + pre[j];
  }
  if (tid == 255) partials[blockIdx.x] = sd[255];
}

__global__ void scan2(int* partials, int nb, int* row_ptr, int n) {
  __shared__ int sd[256];
  int tid = threadIdx.x;
  int v = (tid < nb) ? partials[tid] : 0;
  sd[tid] = v;
  __syncthreads();
  for (int off = 1; off < 256; off <<= 1) {
    int t = (tid >= off) ? sd[tid - off] : 0;
    __syncthreads();
    sd[tid] += t;
    __syncthreads();
  }
  if (tid < nb) partials[tid] = sd[tid] - v;
  if (tid == nb - 1) row_ptr[n] = sd[tid];
}

__global__ void scan3(int* __restrict__ row_ptr, const int* __restrict__ partials, int n) {
  int i = blockIdx.x * 256 + threadIdx.x;
  if (i < n) row_ptr[i] += partials[i >> 11];
}

// --- scatter + gaussian weights: ONE 16B record per edge per layer ----------
__global__ __launch_bounds__(256) void scatter_wgt(
    const void* ei, const float* __restrict__ ea, int E, const int* flag,
    const int* __restrict__ row_ptr, const int* __restrict__ pos,
    const float* __restrict__ mu1, const float* __restrict__ sig1,
    const float* __restrict__ mus, const float* __restrict__ sigs,
    const float* __restrict__ mu2, const float* __restrict__ sig2,
    uint4* __restrict__ wbuf1, uint4* __restrict__ wbuf2) {
  int e = blockIdx.x * 256 + threadIdx.x;
  if (e >= E) return;
  int is64 = *flag;
  int s = load_idx(ei, (size_t)e, is64);
  int d = load_idx(ei, (size_t)E + e, is64);
  int slot = row_ptr[d] + pos[e];
  float p = ea[e];
  float w1[6], w2[5];
#pragma unroll
  for (int k = 0; k < 5; ++k) {
    float sg = sig1[k], df = p - mu1[k];
    w1[k] = __expf(-0.5f / (EPS_SIGMA + sg * sg) * df * df);
  }
  {
    float sg = sigs[0], df = p - mus[0];
    w1[5] = __expf(-0.5f / (EPS_SIGMA + sg * sg) * df * df);
  }
#pragma unroll
  for (int k = 0; k < 5; ++k) {
    float sg = sig2[k], df = p - mu2[k];
    w2[k] = __expf(-0.5f / (EPS_SIGMA + sg * sg) * df * df);
  }
  wbuf1[slot] = make_uint4(pk2(w1[0], w1[1]), pk2(w1[2], w1[3]), pk2(w1[4], w1[5]), (uintT)s);
  wbuf2[slot] = make_uint4(pk2(w2[0], w2[1]), pk2(w2[2], w2[3]), pk2(w2[4], 0.f), (uintT)s);
}

// --- aggregation: wave per node; half-wave per edge; lane = 2 channels ------
template <int KT>
__device__ __forceinline__ void rec_fma2(float2* acc, uint4 r, float xlo, float xhi) {
  {
    float w = bf2f((ushortT)(r.x & 0xffffu));
    acc[0].x = fmaf(w, xlo, acc[0].x);
    acc[0].y = fmaf(w, xhi, acc[0].y);
  }
  if (KT > 1) {
    float w = bf2f((ushortT)(r.x >> 16));
    acc[1].x = fmaf(w, xlo, acc[1].x);
    acc[1].y = fmaf(w, xhi, acc[1].y);
  }
  if (KT > 2) {
    float w = bf2f((ushortT)(r.y & 0xffffu));
    acc[2].x = fmaf(w, xlo, acc[2].x);
    acc[2].y = fmaf(w, xhi, acc[2].y);
  }
  if (KT > 3) {
    float w = bf2f((ushortT)(r.y >> 16));
    acc[3].x = fmaf(w, xlo, acc[3].x);
    acc[3].y = fmaf(w, xhi, acc[3].y);
  }
  if (KT > 4) {
    float w = bf2f((ushortT)(r.z & 0xffffu));
    acc[4].x = fmaf(w, xlo, acc[4].x);
    acc[4].y = fmaf(w, xhi, acc[4].y);
  }
  if (KT > 5) {
    float w = bf2f((ushortT)(r.z >> 16));
    acc[5].x = fmaf(w, xlo, acc[5].x);
    acc[5].y = fmaf(w, xhi, acc[5].y);
  }
}

template <int KT>
__global__ __launch_bounds__(256) void agg_pre(const ushortT* __restrict__ feat,
                                               const int* __restrict__ row_ptr,
                                               const uint4* __restrict__ wbuf,
                                               ushortT* __restrict__ out, int n, int ldo) {
  int node = blockIdx.x * 4 + (threadIdx.x >> 6);
  int lane = threadIdx.x & 63;
  int h = lane >> 5;
  int l2 = lane & 31;
  if (node >= n) return;
  int beg = row_ptr[node], end = row_ptr[node + 1];
  float2 acc[KT];
#pragma unroll
  for (int k = 0; k < KT; ++k) acc[k] = make_float2(0.f, 0.f);
  int i = beg;
  for (; i + 8 <= end; i += 8) {
    uint4 r0 = wbuf[i + 0 + h];
    uint4 r1 = wbuf[i + 2 + h];
    uint4 r2 = wbuf[i + 4 + h];
    uint4 r3 = wbuf[i + 6 + h];
    uintT x0 = *(const uintT*)&feat[((size_t)r0.w << 6) + l2 * 2];
    uintT x1 = *(const uintT*)&feat[((size_t)r1.w << 6) + l2 * 2];
    uintT x2 = *(const uintT*)&feat[((size_t)r2.w << 6) + l2 * 2];
    uintT x3 = *(const uintT*)&feat[((size_t)r3.w << 6) + l2 * 2];
    rec_fma2<KT>(acc, r0, bf2f((ushortT)(x0 & 0xffffu)), bf2f((ushortT)(x0 >> 16)));
    rec_fma2<KT>(acc, r1, bf2f((ushortT)(x1 & 0xffffu)), bf2f((ushortT)(x1 >> 16)));
    rec_fma2<KT>(acc, r2, bf2f((ushortT)(x2 & 0xffffu)), bf2f((ushortT)(x2 >> 16)));
    rec_fma2<KT>(acc, r3, bf2f((ushortT)(x3 & 0xffffu)), bf2f((ushortT)(x3 >> 16)));
  }
  for (; i + 2 <= end; i += 2) {
    uint4 r = wbuf[i + h];
    uintT xb = *(const uintT*)&feat[((size_t)r.w << 6) + l2 * 2];
    rec_fma2<KT>(acc, r, bf2f((ushortT)(xb & 0xffffu)), bf2f((ushortT)(xb >> 16)));
  }
  if (i < end && h == 0) {
    uint4 r = wbuf[i];
    uintT xb = *(const uintT*)&feat[((size_t)r.w << 6) + l2 * 2];
    rec_fma2<KT>(acc, r, bf2f((ushortT)(xb & 0xffffu)), bf2f((ushortT)(xb >> 16)));
  }
  int degi = end - beg;
  float invdeg = 1.0f / (float)(degi > 1 ? degi : 1);
  uintT* outu = (uintT*)out;
  size_t obase = ((size_t)node * ldo) >> 1;
#pragma unroll
  for (int k = 0; k < KT; ++k) {
    float ox = acc[k].x + __shfl_xor(acc[k].x, 32);
    float oy = acc[k].y + __shfl_xor(acc[k].y, 32);
    if (h == 0) outu[obase + k * 32 + l2] = pk2(ox * invdeg, oy * invdeg);
  }
}

// --- B prep: pack [G_rearranged ; root] into MFMA B-fragment layout (bf16) --
__global__ void prep_bm(const float* __restrict__ g, const float* __restrict__ root,
                        ushortT* __restrict__ Bm, int K, int nks) {
  int t = blockIdx.x * 256 + threadIdx.x;
  if (t >= nks * 256) return;
  int ks = t >> 8, rem = t & 255;
  int nt = rem >> 6, lane = rem & 63;
  int kbase = ks * 32 + (lane >> 4) * 8;
  int col = nt * 16 + (lane & 15);
  ushortT o[8];
#pragma unroll
  for (int j = 0; j < 8; ++j) {
    int r = kbase + j;
    float v;
    if (r < K * 64) {
      int k = r >> 6, i = r & 63;
      v = g[(size_t)i * (K * 64) + k * 64 + col];
    } else {
      v = root[(size_t)(r - K * 64) * 64 + col];
    }
    o[j] = f2bf(v);
  }
  *(uint4*)&Bm[(size_t)t * 8] = *(const uint4*)o;
}

// --- BN-stats epilogue helper (device, per-block) ---------------------------
__device__ __forceinline__ void bn_epilogue(float cs[4], float cq[4], int wid, int lane,
                                            int tid, float red_s[4][64], float red_q[4][64],
                                            float* sums, float* sumsq, int row16) {
#pragma unroll
  for (int nt = 0; nt < 4; ++nt) {
    cs[nt] += __shfl_xor(cs[nt], 16);
    cs[nt] += __shfl_xor(cs[nt], 32);
    cq[nt] += __shfl_xor(cq[nt], 16);
    cq[nt] += __shfl_xor(cq[nt], 32);
  }
  if (lane < 16) {
#pragma unroll
    for (int nt = 0; nt < 4; ++nt) {
      red_s[wid][nt * 16 + lane] = cs[nt];
      red_q[wid][nt * 16 + lane] = cq[nt];
    }
  }
  __syncthreads();
  if (tid < 64) {
    float ts = red_s[0][tid] + red_s[1][tid] + red_s[2][tid] + red_s[3][tid];
    float tq = red_q[0][tid] + red_q[1][tid] + red_q[2][tid] + red_q[3][tid];
    atomicAdd(&sums[tid], ts);
    atomicAdd(&sumsq[tid], tq);
  }
  __syncthreads();
}

// --- MFMA GEMM (single): C[M,64] = [A1(K1)|A2(64)]@B + bias ; BN stats ------
__global__ __launch_bounds__(256) void gemm_mfma(const ushortT* __restrict__ A1, int lda1,
                                                 int K1, const ushortT* __restrict__ A2,
                                                 const ushortT* __restrict__ Bm,
                                                 const float* __restrict__ bias,
                                                 float* __restrict__ C, int M,
                                                 float* sums, float* sumsq) {
  __shared__ float red_s[4][64];
  __shared__ float red_q[4][64];
  int tid = threadIdx.x;
  int wid = tid >> 6, lane = tid & 63;
  int row16 = lane & 15, kg = lane >> 4;
  int rowbase = blockIdx.x * 64 + wid * 16;
  int arow = rowbase + row16;
  if (arow >= M) arow = M - 1;
  const ushortT* a1p = A1 + (size_t)arow * lda1 + kg * 8;
  const ushortT* a2p = A2 + (size_t)arow * 64 + kg * 8;
  int nks1 = K1 >> 5;
  int nks = (K1 + 64) >> 5;
  f32x4 acc[4];
#pragma unroll
  for (int nt = 0; nt < 4; ++nt) acc[nt] = (f32x4){0.f, 0.f, 0.f, 0.f};
  for (int ks = 0; ks < nks; ++ks) {
    const ushortT* ap = (ks < nks1) ? (a1p + ks * 32) : (a2p + (ks - nks1) * 32);
    bf16x8 af = *(const bf16x8*)ap;
#pragma unroll
    for (int nt = 0; nt < 4; ++nt) {
      bf16x8 bfr = *(const bf16x8*)(Bm + (size_t)ks * 2048 + nt * 512 + lane * 8);
      acc[nt] = __builtin_amdgcn_mfma_f32_16x16x32_bf16(af, bfr, acc[nt], 0, 0, 0);
    }
  }
  float bv[4];
#pragma unroll
  for (int nt = 0; nt < 4; ++nt) bv[nt] = bias[nt * 16 + row16];
  float cs[4] = {}, cq[4] = {};
#pragma unroll
  for (int r = 0; r < 4; ++r) {
    int orow = rowbase + kg * 4 + r;
    if (orow < M) {
#pragma unroll
      for (int nt = 0; nt < 4; ++nt) {
        float v = acc[nt][r] + bv[nt];
        C[(size_t)orow * 64 + nt * 16 + row16] = v;
        cs[nt] += v;
        cq[nt] = fmaf(v, v, cq[nt]);
      }
    }
  }
  bn_epilogue(cs, cq, wid, lane, tid, red_s, red_q, sums, sumsq, row16);
}

// --- MFMA GEMM (dual): H = [Abuf(0:320)|x]@Bm1+b1 ; S = [Abuf(320:384)|x]@Bmsc+bs
__global__ __launch_bounds__(256) void gemm_mfma_dual(
    const ushortT* __restrict__ Abuf, const ushortT* __restrict__ X,
    const ushortT* __restrict__ Bm1, const ushortT* __restrict__ Bmsc,
    const float* __restrict__ b1, const float* __restrict__ bs,
    float* __restrict__ H, float* __restrict__ S, int M,
    float* sumH, float* sqH, float* sumS, float* sqS) {
  __shared__ float red_s[4][64];
  __shared__ float red_q[4][64];
  int tid = threadIdx.x;
  int wid = tid >> 6, lane = tid & 63;
  int row16 = lane & 15, kg = lane >> 4;
  int rowbase = blockIdx.x * 64 + wid * 16;
  int arow = rowbase + row16;
  if (arow >= M) arow = M - 1;
  const ushortT* ab = Abuf + (size_t)arow * 384 + kg * 8;
  const ushortT* xb = X + (size_t)arow * 64 + kg * 8;
  f32x4 accH[4], accS[4];
#pragma unroll
  for (int nt = 0; nt < 4; ++nt) {
    accH[nt] = (f32x4){0.f, 0.f, 0.f, 0.f};
    accS[nt] = (f32x4){0.f, 0.f, 0.f, 0.f};
  }
  // H main: Abuf cols 0..320 (ks 0..9)
  for (int ks = 0; ks < 10; ++ks) {
    bf16x8 af = *(const bf16x8*)(ab + ks * 32);
#pragma unroll
    for (int nt = 0; nt < 4; ++nt) {
      bf16x8 bfr = *(const bf16x8*)(Bm1 + (size_t)ks * 2048 + nt * 512 + lane * 8);
      accH[nt] = __builtin_amdgcn_mfma_f32_16x16x32_bf16(af, bfr, accH[nt], 0, 0, 0);
    }
  }
  // S part A: Abuf cols 320..384 (Bmsc ks 0..1)
#pragma unroll
  for (int ks = 0; ks < 2; ++ks) {
    bf16x8 af = *(const bf16x8*)(ab + 320 + ks * 32);
#pragma unroll
    for (int nt = 0; nt < 4; ++nt) {
      bf16x8 bfr = *(const bf16x8*)(Bmsc + (size_t)ks * 2048 + nt * 512 + lane * 8);
      accS[nt] = __builtin_amdgcn_mfma_f32_16x16x32_bf16(af, bfr, accS[nt], 0, 0, 0);
    }
  }
  // shared x fragments: H ks 10..11, S ks 2..3
#pragma unroll
  for (int ks = 0; ks < 2; ++ks) {
    bf16x8 af = *(const bf16x8*)(xb + ks * 32);
#pragma unroll
    for (int nt = 0; nt < 4; ++nt) {
      bf16x8 bfrH = *(const bf16x8*)(Bm1 + (size_t)(10 + ks) * 2048 + nt * 512 + lane * 8);
      accH[nt] = __builtin_amdgcn_mfma_f32_16x16x32_bf16(af, bfrH, accH[nt], 0, 0, 0);
      bf16x8 bfrS = *(const bf16x8*)(Bmsc + (size_t)(2 + ks) * 2048 + nt * 512 + lane * 8);
      accS[nt] = __builtin_amdgcn_mfma_f32_16x16x32_bf16(af, bfrS, accS[nt], 0, 0, 0);
    }
  }
  float bvH[4], bvS[4];
#pragma unroll
  for (int nt = 0; nt < 4; ++nt) {
    bvH[nt] = b1[nt * 16 + row16];
    bvS[nt] = bs[nt * 16 + row16];
  }
  float csH[4] = {}, cqH[4] = {}, csS[4] = {}, cqS[4] = {};
#pragma unroll
  for (int r = 0; r < 4; ++r) {
    int orow = rowbase + kg * 4 + r;
    if (orow < M) {
#pragma unroll
      for (int nt = 0; nt < 4; ++nt) {
        float vh = accH[nt][r] + bvH[nt];
        float vs = accS[nt][r] + bvS[nt];
        H[(size_t)orow * 64 + nt * 16 + row16] = vh;
        S[(size_t)orow * 64 + nt * 16 + row16] = vs;
        csH[nt] += vh;
        cqH[nt] = fmaf(vh, vh, cqH[nt]);
        csS[nt] += vs;
        cqS[nt] = fmaf(vs, vs, cqS[nt]);
      }
    }
  }
  bn_epilogue(csH, cqH, wid, lane, tid, red_s, red_q, sumH, sqH, row16);
  bn_epilogue(csS, cqS, wid, lane, tid, red_s, red_q, sumS, sqS, row16);
}

// --- batchnorm scale/shift + epilogues --------------------------------------
__global__ void bn_final(const float* sum, const float* sumsq, const float* gamma,
                         const float* beta, int n, float* scale, float* shift) {
  int c = threadIdx.x;
  float m = sum[c] / (float)n;
  float v = sumsq[c] / (float)n - m * m;
  float r = rsqrtf(v + BN_EPS);
  float s = r * gamma[c];
  scale[c] = s;
  shift[c] = beta[c] - m * s;
}

// normalize + ELU; writes fp32 and bf16 copies
__global__ void norm_elu(float* h, ushortT* __restrict__ h_bf,
                         const float* __restrict__ scale,
                         const float* __restrict__ shift, int total) {
  int i = blockIdx.x * 256 + threadIdx.x;
  if (i >= total) return;
  int c = i & 63;
  float v = h[i] * scale[c] + shift[c];
  v = v > 0.f ? v : expm1f(v);
  h[i] = v;
  h_bf[i] = f2bf(v);
}

__global__ void final_kernel(const float* __restrict__ h2, const float* __restrict__ sc,
                             const float* __restrict__ s2, const float* __restrict__ t2,
                             const float* __restrict__ ss, const float* __restrict__ ts,
                             float* __restrict__ out, int total) {
  int i = blockIdx.x * 256 + threadIdx.x;
  if (i >= total) return;
  int c = i & 63;
  float v = h2[i] * s2[c] + t2[c] + sc[i] * ss[c] + ts[c];
  out[i] = v > 0.f ? v : expm1f(v);
}

// ---------------------------------------------------------------------------
extern "C" void kernel_launch(void* const* d_in, const int* in_sizes, int n_in,
                              void* d_out, int out_size, void* d_ws, size_t ws_size,
                              hipStream_t stream) {
  const float* x    = (const float*)d_in[0];
  const void*  ei   = d_in[1];
  const float* ea   = (const float*)d_in[2];
  const float* g1   = (const float*)d_in[3];
  const float* mu1  = (const float*)d_in[4];
  const float* sig1 = (const float*)d_in[5];
  const float* root1= (const float*)d_in[6];
  const float* b1   = (const float*)d_in[7];
  const float* gam1 = (const float*)d_in[8];
  const float* bet1 = (const float*)d_in[9];
  const float* g2   = (const float*)d_in[10];
  const float* mu2  = (const float*)d_in[11];
  const float* sig2 = (const float*)d_in[12];
  const float* root2= (const float*)d_in[13];
  const float* b2   = (const float*)d_in[14];
  const float* gam2 = (const float*)d_in[15];
  const float* bet2 = (const float*)d_in[16];
  const float* gs   = (const float*)d_in[17];
  const float* mus  = (const float*)d_in[18];
  const float* sigs = (const float*)d_in[19];
  const float* roots= (const float*)d_in[20];
  const float* bs   = (const float*)d_in[21];
  const float* gams = (const float*)d_in[22];
  const float* bets = (const float*)d_in[23];

  int N = in_sizes[0] / 64;
  int E = in_sizes[1] / 2;

  char* w = (char*)d_ws;
  auto alloc = [&](size_t bytes) {
    char* p = w;
    w += (bytes + 255) & ~(size_t)255;
    return p;
  };
  int*     flag    = (int*)alloc(256);
  int*     cnt     = (int*)alloc((size_t)N * 4);
  int*     row_ptr = (int*)alloc((size_t)(N + 1) * 4);
  int*     partials= (int*)alloc(256 * 4);
  int*     pos     = (int*)alloc((size_t)E * 4);
  uint4*   wbuf1   = (uint4*)alloc((size_t)E * 16);        // layer1+sc records
  uint4*   wbuf2   = (uint4*)alloc((size_t)E * 16);        // layer2 records
  ushortT* Abuf    = (ushortT*)alloc((size_t)N * 384 * 2); // agg outputs (bf16)
  ushortT* x_bf    = (ushortT*)alloc((size_t)N * 64 * 2);
  ushortT* h_bf    = (ushortT*)alloc((size_t)N * 64 * 2);
  float*   h       = (float*)alloc((size_t)N * 64 * 4);
  float*   h2      = (float*)alloc((size_t)N * 64 * 4);
  float*   scb     = (float*)alloc((size_t)N * 64 * 4);
  ushortT* Bm1     = (ushortT*)alloc(12 * 2048 * 2);       // MFMA-layout B (bf16)
  ushortT* Bm2     = (ushortT*)alloc(12 * 2048 * 2);
  ushortT* Bmsc    = (ushortT*)alloc(4 * 2048 * 2);
  float*   stats   = (float*)alloc(12 * 64 * 4);

  int eb = (E + 255) / 256;
  int nb1 = (N + 2047) / 2048;
  int nb_elem = (N * 64 + 255) / 256;

  zero_ws<<<(N + 255) / 256, 256, 0, stream>>>(cnt, stats, N);
  prep_bm<<<12, 256, 0, stream>>>(g1, root1, Bm1, 5, 12);
  prep_bm<<<12, 256, 0, stream>>>(g2, root2, Bm2, 5, 12);
  prep_bm<<<4, 256, 0, stream>>>(gs, roots, Bmsc, 1, 4);
  to_bf16<<<(N * 64 / 4 + 255) / 256, 256, 0, stream>>>(x, x_bf, N * 64);

  detect_kernel<<<1, 256, 0, stream>>>(ei, flag);
  hist_kernel<<<eb, 256, 0, stream>>>(ei, E, flag, cnt, pos);
  scan1<<<nb1, 256, 0, stream>>>(cnt, row_ptr, partials, N);
  scan2<<<1, 256, 0, stream>>>(partials, nb1, row_ptr, N);
  scan3<<<(N + 255) / 256, 256, 0, stream>>>(row_ptr, partials, N);
  scatter_wgt<<<eb, 256, 0, stream>>>(ei, ea, E, flag, row_ptr, pos,
                                      mu1, sig1, mus, sigs, mu2, sig2, wbuf1, wbuf2);

  int mtiles = (N + 63) / 64;
  int nb_node = (N + 3) / 4;

  // ---- layer1 + shortcut (one dual-MFMA GEMM) ----
  agg_pre<6><<<nb_node, 256, 0, stream>>>(x_bf, row_ptr, wbuf1, Abuf, N, 384);
  gemm_mfma_dual<<<mtiles, 256, 0, stream>>>(Abuf, x_bf, Bm1, Bmsc, b1, bs, h, scb, N,
                                             stats + 0 * 64, stats + 1 * 64,
                                             stats + 4 * 64, stats + 5 * 64);
  bn_final<<<1, 64, 0, stream>>>(stats + 0 * 64, stats + 1 * 64, gam1, bet1, N,
                                 stats + 6 * 64, stats + 7 * 64);
  norm_elu<<<nb_elem, 256, 0, stream>>>(h, h_bf, stats + 6 * 64, stats + 7 * 64, N * 64);

  // ---- layer2 ----
  agg_pre<5><<<nb_node, 256, 0, stream>>>(h_bf, row_ptr, wbuf2, Abuf, N, 320);
  gemm_mfma<<<mtiles, 256, 0, stream>>>(Abuf, 320, 320, h_bf, Bm2, b2, h2, N,
                                        stats + 2 * 64, stats + 3 * 64);

  bn_final<<<1, 64, 0, stream>>>(stats + 2 * 64, stats + 3 * 64, gam2, bet2, N,
                                 stats + 8 * 64, stats + 9 * 64);
  bn_final<<<1, 64, 0, stream>>>(stats + 4 * 64, stats + 5 * 64, gams, bets, N,
                                 stats + 10 * 64, stats + 11 * 64);

  final_kernel<<<nb_elem, 256, 0, stream>>>(h2, scb, stats + 8 * 64, stats + 9 * 64,
                                            stats + 10 * 64, stats + 11 * 64,
                                            (float*)d_out, N * 64);
}